// Round 1
// baseline (2630.861 us; speedup 1.0000x reference)
//
#include <hip/hip_runtime.h>
#include <hip/hip_bf16.h>
#include <math.h>

#define D_MODEL 1024
#define D_STATE 64
#define D_CONV  4
#define D_INNER 2048
#define N_HEADS 8
#define D_HEAD  256
#define BATCH   2
#define SEQ     2048
#define ROWS    (BATCH*SEQ)   /* 4096 */
#define EPS     1e-6f

__device__ __forceinline__ float silu_f(float x){ return x / (1.0f + __expf(-x)); }
__device__ __forceinline__ float softplus_f(float x){ return (x > 20.0f) ? x : log1pf(__expf(x)); }

// ---------------- RMSNorm: one block per row of 1024 ----------------
__global__ __launch_bounds__(256) void rmsnorm_kernel(const float* __restrict__ x,
                                                      const float* __restrict__ w,
                                                      float* __restrict__ xn){
    int row = blockIdx.x;
    int tid = threadIdx.x;
    const float4* xr = (const float4*)(x + (size_t)row * D_MODEL);
    float4 a = xr[tid];
    float ss = a.x*a.x + a.y*a.y + a.z*a.z + a.w*a.w;
    #pragma unroll
    for (int i = 1; i < 64; i <<= 1) ss += __shfl_xor(ss, i);
    __shared__ float red[4];
    int lane = tid & 63, wid = tid >> 6;
    if (lane == 0) red[wid] = ss;
    __syncthreads();
    float tot = red[0] + red[1] + red[2] + red[3];
    float scale = rsqrtf(tot * (1.0f / D_MODEL) + EPS);
    float4 wv = ((const float4*)w)[tid];
    float4 o;
    o.x = a.x * scale * wv.x;
    o.y = a.y * scale * wv.y;
    o.z = a.z * scale * wv.z;
    o.w = a.w * scale * wv.w;
    ((float4*)(xn + (size_t)row * D_MODEL))[tid] = o;
}

// ---------------- fp32 NT GEMM: C[M][N] = A[M][K] * W[N][K]^T (+resid) ----------------
// 128x128 tile, BK=16, 256 threads, 8x8 per thread.
template<bool RESID>
__global__ __launch_bounds__(256) void gemm_nt_kernel(const float* __restrict__ A,
                                                      const float* __restrict__ W,
                                                      float* __restrict__ C,
                                                      const float* __restrict__ resid,
                                                      int M, int N, int K,
                                                      int lda, int ldw, int ldc){
    __shared__ float As[16][128];
    __shared__ float Bs[16][128];
    int tid = threadIdx.x;
    int m0 = blockIdx.y * 128;
    int n0 = blockIdx.x * 128;
    int tm = tid >> 4, tn = tid & 15;
    float acc[8][8];
    #pragma unroll
    for (int i = 0; i < 8; ++i)
        #pragma unroll
        for (int j = 0; j < 8; ++j) acc[i][j] = 0.f;

    for (int k0 = 0; k0 < K; k0 += 16){
        #pragma unroll
        for (int it = 0; it < 2; ++it){
            int li = tid + it*256;         // 0..511
            int r  = li >> 2;
            int kq = li & 3;
            float4 av = *(const float4*)(A + (size_t)(m0 + r)*lda + k0 + kq*4);
            As[kq*4+0][r] = av.x; As[kq*4+1][r] = av.y;
            As[kq*4+2][r] = av.z; As[kq*4+3][r] = av.w;
            float4 wv = *(const float4*)(W + (size_t)(n0 + r)*ldw + k0 + kq*4);
            Bs[kq*4+0][r] = wv.x; Bs[kq*4+1][r] = wv.y;
            Bs[kq*4+2][r] = wv.z; Bs[kq*4+3][r] = wv.w;
        }
        __syncthreads();
        #pragma unroll
        for (int k = 0; k < 16; ++k){
            float4 a0 = *(const float4*)&As[k][tm*8];
            float4 a1 = *(const float4*)&As[k][tm*8+4];
            float4 b0 = *(const float4*)&Bs[k][tn*8];
            float4 b1 = *(const float4*)&Bs[k][tn*8+4];
            float av[8] = {a0.x,a0.y,a0.z,a0.w,a1.x,a1.y,a1.z,a1.w};
            float bv[8] = {b0.x,b0.y,b0.z,b0.w,b1.x,b1.y,b1.z,b1.w};
            #pragma unroll
            for (int i = 0; i < 8; ++i)
                #pragma unroll
                for (int j = 0; j < 8; ++j)
                    acc[i][j] += av[i]*bv[j];
        }
        __syncthreads();
    }
    #pragma unroll
    for (int i = 0; i < 8; ++i){
        int r = m0 + tm*8 + i;
        float* crow = C + (size_t)r*ldc + n0 + tn*8;
        if (RESID){
            const float* rrow = resid + (size_t)r*ldc + n0 + tn*8;
            #pragma unroll
            for (int j = 0; j < 8; ++j) crow[j] = acc[i][j] + rrow[j];
        } else {
            #pragma unroll
            for (int j = 0; j < 8; ++j) crow[j] = acc[i][j];
        }
    }
}

// ---------------- depthwise causal conv (K=4) + SiLU ----------------
__global__ __launch_bounds__(256) void conv_silu_kernel(const float* __restrict__ xp,
                                                        const float* __restrict__ cw,
                                                        const float* __restrict__ cb,
                                                        float* __restrict__ xs){
    int idx = blockIdx.x * 256 + threadIdx.x;   // over ROWS*D_INNER
    int c = idx & (D_INNER - 1);
    int r = idx >> 11;
    int t = r & (SEQ - 1);
    float acc = cb[c];
    #pragma unroll
    for (int j = 0; j < 4; ++j){
        int tt = t - 3 + j;
        if (tt >= 0) acc += xp[(size_t)(r - 3 + j)*D_INNER + c] * cw[c*4 + j];
    }
    xs[idx] = silu_f(acc);
}

// ---------------- dt = softplus(xs @ dt_w^T + dt_b), per row ----------------
__global__ __launch_bounds__(256) void dt_kernel(const float* __restrict__ xs,
                                                 const float* __restrict__ dt_w,
                                                 const float* __restrict__ dt_b,
                                                 float* __restrict__ dt){
    __shared__ float sx[D_INNER];
    __shared__ float red[4];
    int row = blockIdx.x, tid = threadIdx.x;
    const float4* xr = (const float4*)(xs + (size_t)row * D_INNER);
    ((float4*)sx)[tid]       = xr[tid];
    ((float4*)sx)[tid + 256] = xr[tid + 256];
    __syncthreads();
    int lane = tid & 63, wid = tid >> 6;
    for (int h = 0; h < N_HEADS; ++h){
        float p = 0.f;
        for (int k = tid; k < D_INNER; k += 256) p += sx[k] * dt_w[h*D_INNER + k];
        #pragma unroll
        for (int i = 1; i < 64; i <<= 1) p += __shfl_xor(p, i);
        if (lane == 0) red[wid] = p;
        __syncthreads();
        if (tid == 0){
            float s = red[0]+red[1]+red[2]+red[3] + dt_b[h];
            dt[(size_t)row*N_HEADS + h] = softplus_f(s);
        }
        __syncthreads();
    }
}

// ---------------- sequential SSM scan, fused D-skip + silu(z) gating ----------------
// grid (4, 8, 2): (d-quarter, head, batch). 256 threads: thread = (d_local = tid>>2, g = tid&3)
// state h[n][d]: thread holds n = g*16 .. g*16+15 for its d column -> 16 registers.
__global__ __launch_bounds__(256) void scan_kernel(const float* __restrict__ xs,
                                                   const float* __restrict__ z,
                                                   const float* __restrict__ dtv,
                                                   const float* __restrict__ Bm,
                                                   const float* __restrict__ Cm,
                                                   const float* __restrict__ A_log,
                                                   const float* __restrict__ Dp,
                                                   float* __restrict__ y){
    int dq = blockIdx.x;
    int h  = blockIdx.y;
    int b  = blockIdx.z;
    int tid = threadIdx.x;
    int dl = tid >> 2, g = tid & 3;
    float Ah = -__expf(A_log[h]);
    float Dh = Dp[h];
    __shared__ float sB[64], sC[64], sX[64];
    __shared__ float sdt;
    float hreg[16];
    #pragma unroll
    for (int i = 0; i < 16; ++i) hreg[i] = 0.f;

    size_t row0 = (size_t)b * SEQ;
    int cbase = h*D_HEAD + dq*64;
    float pB = 0.f, pC = 0.f, pX = 0.f, pdt = 0.f;
    {
        size_t row = row0;
        if      (tid < 64)  pB  = Bm[row*512 + h*64 + tid];
        else if (tid < 128) pC  = Cm[row*512 + h*64 + (tid-64)];
        else if (tid < 192) pX  = xs[row*D_INNER + cbase + (tid-128)];
        else if (tid == 192) pdt = dtv[row*N_HEADS + h];
    }
    for (int t = 0; t < SEQ; ++t){
        __syncthreads();
        if      (tid < 64)  sB[tid]     = pB;
        else if (tid < 128) sC[tid-64]  = pC;
        else if (tid < 192) sX[tid-128] = pX;
        else if (tid == 192) sdt = pdt;
        __syncthreads();
        if (t + 1 < SEQ){
            size_t row = row0 + t + 1;
            if      (tid < 64)  pB  = Bm[row*512 + h*64 + tid];
            else if (tid < 128) pC  = Cm[row*512 + h*64 + (tid-64)];
            else if (tid < 192) pX  = xs[row*D_INNER + cbase + (tid-128)];
            else if (tid == 192) pdt = dtv[row*N_HEADS + h];
        }
        float dts = sdt;
        float dA  = __expf(dts * Ah);
        float xd  = sX[dl];
        float bx  = dts * xd;
        float ys  = 0.f;
        #pragma unroll
        for (int i = 0; i < 16; ++i){
            int n = g*16 + i;
            hreg[i] = dA*hreg[i] + sB[n]*bx;
            ys += sC[n]*hreg[i];
        }
        ys += __shfl_xor(ys, 1);
        ys += __shfl_xor(ys, 2);
        if (g == 0){
            size_t row = row0 + t;
            size_t idx = row*D_INNER + cbase + dl;
            y[idx] = (ys + Dh*xd) * silu_f(z[idx]);
        }
    }
}

// ---------------- launch ----------------
extern "C" void kernel_launch(void* const* d_in, const int* in_sizes, int n_in,
                              void* d_out, int out_size, void* d_ws, size_t ws_size,
                              hipStream_t stream){
    const float* x      = (const float*)d_in[0];
    const float* norm_w = (const float*)d_in[1];
    const float* in_w   = (const float*)d_in[2];
    const float* conv_w = (const float*)d_in[3];
    const float* conv_b = (const float*)d_in[4];
    const float* A_log  = (const float*)d_in[5];
    const float* B_w    = (const float*)d_in[6];
    const float* C_w    = (const float*)d_in[7];
    const float* dt_w   = (const float*)d_in[8];
    const float* dt_b   = (const float*)d_in[9];
    const float* Dp     = (const float*)d_in[10];
    const float* out_w  = (const float*)d_in[11];
    float* out = (float*)d_out;

    char* ws = (char*)d_ws;
    float* xn   = (float*)(ws);                                   // 4096*1024 f32 = 16 MB
    float* xpre = (float*)(ws + (size_t)16777216);                // 4096*2048 f32 = 32 MB
    float* zbuf = (float*)(ws + (size_t)16777216 + 33554432);     // 32 MB
    float* xs   = (float*)(ws + (size_t)16777216 + 2u*33554432);  // 32 MB
    float* dtb  = (float*)(ws + (size_t)16777216 + 3u*33554432);  // 128 KB
    float* Bm   = (float*)(ws + (size_t)16777216 + 3u*33554432 + 131072);            // 8 MB
    float* Cm   = (float*)(ws + (size_t)16777216 + 3u*33554432 + 131072 + 8388608);  // 8 MB
    float* y    = xpre;  // xpre is dead after conv; reuse for gated y

    rmsnorm_kernel<<<ROWS, 256, 0, stream>>>(x, norm_w, xn);

    // in_proj split halves: x_pre = xn @ in_w[0:2048]^T ; z = xn @ in_w[2048:4096]^T
    gemm_nt_kernel<false><<<dim3(16,32), 256, 0, stream>>>(xn, in_w,              xpre, nullptr,
                                                           ROWS, D_INNER, D_MODEL, D_MODEL, D_MODEL, D_INNER);
    gemm_nt_kernel<false><<<dim3(16,32), 256, 0, stream>>>(xn, in_w + (size_t)D_INNER*D_MODEL, zbuf, nullptr,
                                                           ROWS, D_INNER, D_MODEL, D_MODEL, D_MODEL, D_INNER);

    conv_silu_kernel<<<(ROWS*D_INNER)/256, 256, 0, stream>>>(xpre, conv_w, conv_b, xs);

    dt_kernel<<<ROWS, 256, 0, stream>>>(xs, dt_w, dt_b, dtb);

    gemm_nt_kernel<false><<<dim3(4,32), 256, 0, stream>>>(xs, B_w, Bm, nullptr,
                                                          ROWS, 512, D_INNER, D_INNER, D_INNER, 512);
    gemm_nt_kernel<false><<<dim3(4,32), 256, 0, stream>>>(xs, C_w, Cm, nullptr,
                                                          ROWS, 512, D_INNER, D_INNER, D_INNER, 512);

    scan_kernel<<<dim3(4, N_HEADS, BATCH), 256, 0, stream>>>(xs, zbuf, dtb, Bm, Cm, A_log, Dp, y);

    // out = x + y @ out_w^T
    gemm_nt_kernel<true><<<dim3(8,32), 256, 0, stream>>>(y, out_w, out, x,
                                                         ROWS, D_MODEL, D_INNER, D_INNER, D_INNER, D_MODEL);
}

// Round 2
// 1532.452 us; speedup vs baseline: 1.7168x; 1.7168x over previous
//
#include <hip/hip_runtime.h>
#include <hip/hip_bf16.h>
#include <math.h>

#define D_MODEL 1024
#define D_STATE 64
#define D_CONV  4
#define D_INNER 2048
#define N_HEADS 8
#define D_HEAD  256
#define BATCH   2
#define SEQ     2048
#define ROWS    (BATCH*SEQ)   /* 4096 */
#define NCHUNK  32            /* SEQ/64 */
#define EPS     1e-6f

typedef __attribute__((ext_vector_type(4))) unsigned short ushort4v;
typedef __attribute__((ext_vector_type(8))) unsigned short ushort8v;

__device__ __forceinline__ float silu_f(float x){ return x / (1.0f + __expf(-x)); }
__device__ __forceinline__ float softplus_f(float x){ return (x > 20.0f) ? x : log1pf(__expf(x)); }
__device__ __forceinline__ float bf2f(unsigned short u){
    union { unsigned int i; float f; } v; v.i = ((unsigned int)u) << 16; return v.f;
}

// ---------------- RMSNorm ----------------
__global__ __launch_bounds__(256) void rmsnorm_kernel(const float* __restrict__ x,
                                                      const float* __restrict__ w,
                                                      float* __restrict__ xn){
    int row = blockIdx.x;
    int tid = threadIdx.x;
    const float4* xr = (const float4*)(x + (size_t)row * D_MODEL);
    float4 a = xr[tid];
    float ss = a.x*a.x + a.y*a.y + a.z*a.z + a.w*a.w;
    #pragma unroll
    for (int i = 1; i < 64; i <<= 1) ss += __shfl_xor(ss, i);
    __shared__ float red[4];
    int lane = tid & 63, wid = tid >> 6;
    if (lane == 0) red[wid] = ss;
    __syncthreads();
    float tot = red[0] + red[1] + red[2] + red[3];
    float scale = rsqrtf(tot * (1.0f / D_MODEL) + EPS);
    float4 wv = ((const float4*)w)[tid];
    float4 o;
    o.x = a.x * scale * wv.x;
    o.y = a.y * scale * wv.y;
    o.z = a.z * scale * wv.z;
    o.w = a.w * scale * wv.w;
    ((float4*)(xn + (size_t)row * D_MODEL))[tid] = o;
}

// ---------------- fp32 NT GEMM (in_proj, out_proj) ----------------
template<bool RESID>
__global__ __launch_bounds__(256) void gemm_nt_kernel(const float* __restrict__ A,
                                                      const float* __restrict__ W,
                                                      float* __restrict__ C,
                                                      const float* __restrict__ resid,
                                                      int M, int N, int K,
                                                      int lda, int ldw, int ldc){
    __shared__ float As[16][128];
    __shared__ float Bs[16][128];
    int tid = threadIdx.x;
    int m0 = blockIdx.y * 128;
    int n0 = blockIdx.x * 128;
    int tm = tid >> 4, tn = tid & 15;
    float acc[8][8];
    #pragma unroll
    for (int i = 0; i < 8; ++i)
        #pragma unroll
        for (int j = 0; j < 8; ++j) acc[i][j] = 0.f;

    for (int k0 = 0; k0 < K; k0 += 16){
        #pragma unroll
        for (int it = 0; it < 2; ++it){
            int li = tid + it*256;
            int r  = li >> 2;
            int kq = li & 3;
            float4 av = *(const float4*)(A + (size_t)(m0 + r)*lda + k0 + kq*4);
            As[kq*4+0][r] = av.x; As[kq*4+1][r] = av.y;
            As[kq*4+2][r] = av.z; As[kq*4+3][r] = av.w;
            float4 wv = *(const float4*)(W + (size_t)(n0 + r)*ldw + k0 + kq*4);
            Bs[kq*4+0][r] = wv.x; Bs[kq*4+1][r] = wv.y;
            Bs[kq*4+2][r] = wv.z; Bs[kq*4+3][r] = wv.w;
        }
        __syncthreads();
        #pragma unroll
        for (int k = 0; k < 16; ++k){
            float4 a0 = *(const float4*)&As[k][tm*8];
            float4 a1 = *(const float4*)&As[k][tm*8+4];
            float4 b0 = *(const float4*)&Bs[k][tn*8];
            float4 b1 = *(const float4*)&Bs[k][tn*8+4];
            float av[8] = {a0.x,a0.y,a0.z,a0.w,a1.x,a1.y,a1.z,a1.w};
            float bv[8] = {b0.x,b0.y,b0.z,b0.w,b1.x,b1.y,b1.z,b1.w};
            #pragma unroll
            for (int i = 0; i < 8; ++i)
                #pragma unroll
                for (int j = 0; j < 8; ++j)
                    acc[i][j] += av[i]*bv[j];
        }
        __syncthreads();
    }
    #pragma unroll
    for (int i = 0; i < 8; ++i){
        int r = m0 + tm*8 + i;
        float* crow = C + (size_t)r*ldc + n0 + tn*8;
        if (RESID){
            const float* rrow = resid + (size_t)r*ldc + n0 + tn*8;
            #pragma unroll
            for (int j = 0; j < 8; ++j) crow[j] = acc[i][j] + rrow[j];
        } else {
            #pragma unroll
            for (int j = 0; j < 8; ++j) crow[j] = acc[i][j];
        }
    }
}

// ---------------- NT GEMM, bf16 A input, bf16 output (B/C projections) ----------------
__global__ __launch_bounds__(256) void gemm_bf16a_kernel(const __hip_bfloat16* __restrict__ A,
                                                         const float* __restrict__ W,
                                                         __hip_bfloat16* __restrict__ C,
                                                         int M, int N, int K,
                                                         int lda, int ldw, int ldc){
    __shared__ float As[16][128];
    __shared__ float Bs[16][128];
    int tid = threadIdx.x;
    int m0 = blockIdx.y * 128;
    int n0 = blockIdx.x * 128;
    int tm = tid >> 4, tn = tid & 15;
    float acc[8][8];
    #pragma unroll
    for (int i = 0; i < 8; ++i)
        #pragma unroll
        for (int j = 0; j < 8; ++j) acc[i][j] = 0.f;

    for (int k0 = 0; k0 < K; k0 += 16){
        #pragma unroll
        for (int it = 0; it < 2; ++it){
            int li = tid + it*256;
            int r  = li >> 2;
            int kq = li & 3;
            ushort4v av = *(const ushort4v*)((const unsigned short*)A + (size_t)(m0 + r)*lda + k0 + kq*4);
            As[kq*4+0][r] = bf2f(av[0]); As[kq*4+1][r] = bf2f(av[1]);
            As[kq*4+2][r] = bf2f(av[2]); As[kq*4+3][r] = bf2f(av[3]);
            float4 wv = *(const float4*)(W + (size_t)(n0 + r)*ldw + k0 + kq*4);
            Bs[kq*4+0][r] = wv.x; Bs[kq*4+1][r] = wv.y;
            Bs[kq*4+2][r] = wv.z; Bs[kq*4+3][r] = wv.w;
        }
        __syncthreads();
        #pragma unroll
        for (int k = 0; k < 16; ++k){
            float4 a0 = *(const float4*)&As[k][tm*8];
            float4 a1 = *(const float4*)&As[k][tm*8+4];
            float4 b0 = *(const float4*)&Bs[k][tn*8];
            float4 b1 = *(const float4*)&Bs[k][tn*8+4];
            float av[8] = {a0.x,a0.y,a0.z,a0.w,a1.x,a1.y,a1.z,a1.w};
            float bv[8] = {b0.x,b0.y,b0.z,b0.w,b1.x,b1.y,b1.z,b1.w};
            #pragma unroll
            for (int i = 0; i < 8; ++i)
                #pragma unroll
                for (int j = 0; j < 8; ++j)
                    acc[i][j] += av[i]*bv[j];
        }
        __syncthreads();
    }
    #pragma unroll
    for (int i = 0; i < 8; ++i){
        int r = m0 + tm*8 + i;
        __hip_bfloat16* crow = C + (size_t)r*ldc + n0 + tn*8;
        #pragma unroll
        for (int j = 0; j < 8; ++j) crow[j] = __float2bfloat16(acc[i][j]);
    }
}

// ---------------- depthwise causal conv (K=4) + SiLU -> bf16 ----------------
__global__ __launch_bounds__(256) void conv_silu_kernel(const float* __restrict__ xp,
                                                        const float* __restrict__ cw,
                                                        const float* __restrict__ cb,
                                                        __hip_bfloat16* __restrict__ xs){
    int idx = blockIdx.x * 256 + threadIdx.x;
    int c = idx & (D_INNER - 1);
    int r = idx >> 11;
    int t = r & (SEQ - 1);
    float acc = cb[c];
    #pragma unroll
    for (int j = 0; j < 4; ++j){
        int tt = t - 3 + j;
        if (tt >= 0) acc += xp[(size_t)(r - 3 + j)*D_INNER + c] * cw[c*4 + j];
    }
    xs[idx] = __float2bfloat16(silu_f(acc));
}

// ---------------- dt = softplus(xs @ dt_w^T + dt_b) ----------------
__global__ __launch_bounds__(256) void dt_kernel(const __hip_bfloat16* __restrict__ xs,
                                                 const float* __restrict__ dt_w,
                                                 const float* __restrict__ dt_b,
                                                 float* __restrict__ dt){
    __shared__ float sx[D_INNER];
    __shared__ float red[4];
    int row = blockIdx.x, tid = threadIdx.x;
    ushort8v v = ((const ushort8v*)((const unsigned short*)xs + (size_t)row * D_INNER))[tid];
    #pragma unroll
    for (int j = 0; j < 8; ++j) sx[tid*8 + j] = bf2f(v[j]);
    __syncthreads();
    int lane = tid & 63, wid = tid >> 6;
    for (int h = 0; h < N_HEADS; ++h){
        float p = 0.f;
        for (int k = tid; k < D_INNER; k += 256) p += sx[k] * dt_w[h*D_INNER + k];
        #pragma unroll
        for (int i = 1; i < 64; i <<= 1) p += __shfl_xor(p, i);
        if (lane == 0) red[wid] = p;
        __syncthreads();
        if (tid == 0){
            float s = red[0]+red[1]+red[2]+red[3] + dt_b[h];
            dt[(size_t)row*N_HEADS + h] = softplus_f(s);
        }
        __syncthreads();
    }
}

// ---------------- per-chunk inclusive prefix of a_t = dt_t * A_h ----------------
__global__ __launch_bounds__(64) void cums_kernel(const float* __restrict__ dtb,
                                                  const float* __restrict__ A_log,
                                                  float* __restrict__ cums){
    int c = blockIdx.x, h = blockIdx.y, b = blockIdx.z;
    int lane = threadIdx.x;
    int t = c*64 + lane;
    float Ah = -__expf(A_log[h]);
    float a = dtb[(size_t)(b*SEQ + t)*N_HEADS + h] * Ah;
    #pragma unroll
    for (int i = 1; i < 64; i <<= 1){
        float v = __shfl_up(a, i);
        if (lane >= i) a += v;
    }
    cums[((size_t)(b*N_HEADS + h))*SEQ + t] = a;
}

// ---------------- per-chunk state contribution: S = Bw^T @ Xd (64x256) ----------------
__global__ __launch_bounds__(256) void chunk_state_kernel(const __hip_bfloat16* __restrict__ xs,
                                                          const __hip_bfloat16* __restrict__ Bm,
                                                          const float* __restrict__ dtb,
                                                          const float* __restrict__ cums,
                                                          float* __restrict__ HS){
    int c = blockIdx.x, h = blockIdx.y, b = blockIdx.z;
    int tid = threadIdx.x;
    int bh = b*N_HEADS + h;
    int t0 = c*64;
    float cumtot = cums[(size_t)bh*SEQ + t0 + 63];
    __shared__ float sB[16][65];
    __shared__ float sX[16][256];
    float acc[8][8];
    #pragma unroll
    for (int i = 0; i < 8; ++i)
        #pragma unroll
        for (int j = 0; j < 8; ++j) acc[i][j] = 0.f;
    int tm = tid >> 5, tn = tid & 31;
    int trL = tid >> 4, seg = tid & 15;

    for (int kt = 0; kt < 4; ++kt){
        int t = t0 + kt*16 + trL;
        int row = b*SEQ + t;
        float wdecay = __expf(cumtot - cums[(size_t)bh*SEQ + t]);
        ushort4v bv = *(const ushort4v*)((const unsigned short*)Bm + (size_t)row*512 + h*64 + seg*4);
        sB[trL][seg*4+0] = bf2f(bv[0])*wdecay;
        sB[trL][seg*4+1] = bf2f(bv[1])*wdecay;
        sB[trL][seg*4+2] = bf2f(bv[2])*wdecay;
        sB[trL][seg*4+3] = bf2f(bv[3])*wdecay;
        float dtv = dtb[(size_t)row*N_HEADS + h];
        const unsigned short* xp = (const unsigned short*)xs + (size_t)row*D_INNER + h*D_HEAD + seg*16;
        ushort8v x0 = ((const ushort8v*)xp)[0];
        ushort8v x1 = ((const ushort8v*)xp)[1];
        #pragma unroll
        for (int j = 0; j < 8; ++j){
            sX[trL][seg*16 + j]     = bf2f(x0[j])*dtv;
            sX[trL][seg*16 + 8 + j] = bf2f(x1[j])*dtv;
        }
        __syncthreads();
        #pragma unroll
        for (int k = 0; k < 16; ++k){
            float a[8], bb[8];
            #pragma unroll
            for (int i = 0; i < 8; ++i) a[i] = sB[k][tm*8+i];
            float4 b0 = *(const float4*)&sX[k][tn*8];
            float4 b1 = *(const float4*)&sX[k][tn*8+4];
            bb[0]=b0.x; bb[1]=b0.y; bb[2]=b0.z; bb[3]=b0.w;
            bb[4]=b1.x; bb[5]=b1.y; bb[6]=b1.z; bb[7]=b1.w;
            #pragma unroll
            for (int i = 0; i < 8; ++i)
                #pragma unroll
                for (int j = 0; j < 8; ++j)
                    acc[i][j] += a[i]*bb[j];
        }
        __syncthreads();
    }
    float* out = HS + ((size_t)bh*NCHUNK + c)*16384;
    #pragma unroll
    for (int i = 0; i < 8; ++i){
        float* orow = out + (tm*8+i)*256 + tn*8;
        *(float4*)orow     = make_float4(acc[i][0],acc[i][1],acc[i][2],acc[i][3]);
        *(float4*)(orow+4) = make_float4(acc[i][4],acc[i][5],acc[i][6],acc[i][7]);
    }
}

// ---------------- sequential pass over chunks: HS[c] := H_start(c), in place ----------------
__global__ __launch_bounds__(256) void state_pass_kernel(const float* __restrict__ cums,
                                                         float* __restrict__ HS){
    int bh = blockIdx.x;
    int tid = threadIdx.x;
    float H[64];
    #pragma unroll
    for (int i = 0; i < 64; ++i) H[i] = 0.f;
    size_t base = (size_t)bh * NCHUNK * 16384;
    for (int c = 0; c < NCHUNK; ++c){
        float Pc = __expf(cums[(size_t)bh*SEQ + c*64 + 63]);
        float* p = HS + base + (size_t)c*16384 + tid;
        #pragma unroll
        for (int i = 0; i < 64; ++i){
            float s = p[i*256];
            p[i*256] = H[i];
            H[i] = fmaf(Pc, H[i], s);
        }
    }
}

// ---------------- per-chunk output: Y = (decay∘(C@B^T))@Xd + (decay·C)@H + D-skip, gated ----------------
__global__ __launch_bounds__(256) void chunk_out_kernel(const __hip_bfloat16* __restrict__ xs,
                                                        const float* __restrict__ zbuf,
                                                        const __hip_bfloat16* __restrict__ Bm,
                                                        const __hip_bfloat16* __restrict__ Cm,
                                                        const float* __restrict__ dtb,
                                                        const float* __restrict__ cums,
                                                        const float* __restrict__ HS,
                                                        const float* __restrict__ Dp,
                                                        float* __restrict__ y){
    int c = blockIdx.x, h = blockIdx.y, b = blockIdx.z;
    int tid = threadIdx.x;
    int bh = b*N_HEADS + h;
    int t0 = c*64;
    __shared__ float sC[64][65];
    __shared__ float sB[64][65];   // later reused as sBt[16][256]
    __shared__ float sW[64][65];
    __shared__ float scum[64];
    float (*sBt)[256] = reinterpret_cast<float(*)[256]>(&sB[0][0]);

    // load C, B (bf16 -> f32), cums
    int trL = tid >> 2, segL = tid & 3;
    {
        int row = b*SEQ + t0 + trL;
        const unsigned short* cp = (const unsigned short*)Cm + (size_t)row*512 + h*64 + segL*16;
        const unsigned short* bp = (const unsigned short*)Bm + (size_t)row*512 + h*64 + segL*16;
        ushort8v c0 = ((const ushort8v*)cp)[0], c1 = ((const ushort8v*)cp)[1];
        ushort8v b0 = ((const ushort8v*)bp)[0], b1 = ((const ushort8v*)bp)[1];
        #pragma unroll
        for (int j = 0; j < 8; ++j){
            sC[trL][segL*16 + j]     = bf2f(c0[j]);
            sC[trL][segL*16 + 8 + j] = bf2f(c1[j]);
            sB[trL][segL*16 + j]     = bf2f(b0[j]);
            sB[trL][segL*16 + 8 + j] = bf2f(b1[j]);
        }
        if (tid < 64) scum[tid] = cums[(size_t)bh*SEQ + t0 + tid];
    }
    __syncthreads();

    // G = C @ B^T (64x64), then W[t][s] = mask * exp(cum[t]-cum[s]) * G
    int tG = (tid >> 4) * 4, sG = (tid & 15) * 4;
    float g[4][4];
    #pragma unroll
    for (int i = 0; i < 4; ++i)
        #pragma unroll
        for (int j = 0; j < 4; ++j) g[i][j] = 0.f;
    for (int n = 0; n < 64; ++n){
        float a[4], bb[4];
        #pragma unroll
        for (int i = 0; i < 4; ++i) a[i] = sC[tG+i][n];
        #pragma unroll
        for (int j = 0; j < 4; ++j) bb[j] = sB[sG+j][n];
        #pragma unroll
        for (int i = 0; i < 4; ++i)
            #pragma unroll
            for (int j = 0; j < 4; ++j) g[i][j] += a[i]*bb[j];
    }
    #pragma unroll
    for (int i = 0; i < 4; ++i){
        int t = tG + i;
        #pragma unroll
        for (int j = 0; j < 4; ++j){
            int s = sG + j;
            sW[t][s] = (s <= t) ? __expf(scum[t]-scum[s]) * g[i][j] : 0.f;
        }
    }
    __syncthreads();
    // Cd[t][n] = exp(cum[t]) * C[t][n], in place
    {
        float ef = __expf(scum[trL]);
        #pragma unroll
        for (int j = 0; j < 16; ++j) sC[trL][segL*16 + j] *= ef;
    }
    __syncthreads();

    // Y(64x256) = [W | Cd](64x128) @ [Xd ; H](128x256)
    float acc[8][8];
    #pragma unroll
    for (int i = 0; i < 8; ++i)
        #pragma unroll
        for (int j = 0; j < 8; ++j) acc[i][j] = 0.f;
    int tm = tid >> 5, tn = tid & 31;
    int trX = tid >> 4, seg = tid & 15;
    size_t hsbase = ((size_t)bh*NCHUNK + c)*16384;

    for (int kt = 0; kt < 8; ++kt){
        if (kt < 4){
            int t = t0 + kt*16 + trX;
            int row = b*SEQ + t;
            float dtv = dtb[(size_t)row*N_HEADS + h];
            const unsigned short* xp = (const unsigned short*)xs + (size_t)row*D_INNER + h*D_HEAD + seg*16;
            ushort8v x0 = ((const ushort8v*)xp)[0];
            ushort8v x1 = ((const ushort8v*)xp)[1];
            #pragma unroll
            for (int j = 0; j < 8; ++j){
                sBt[trX][seg*16 + j]     = bf2f(x0[j])*dtv;
                sBt[trX][seg*16 + 8 + j] = bf2f(x1[j])*dtv;
            }
        } else {
            int n = (kt-4)*16 + trX;
            const float* hp = HS + hsbase + (size_t)n*256 + seg*16;
            float4 h0 = ((const float4*)hp)[0];
            float4 h1 = ((const float4*)hp)[1];
            float4 h2 = ((const float4*)hp)[2];
            float4 h3 = ((const float4*)hp)[3];
            *(float4*)&sBt[trX][seg*16+0]  = h0;
            *(float4*)&sBt[trX][seg*16+4]  = h1;
            *(float4*)&sBt[trX][seg*16+8]  = h2;
            *(float4*)&sBt[trX][seg*16+12] = h3;
        }
        __syncthreads();
        const float* Abase = (kt < 4) ? &sW[0][0] : &sC[0][0];
        int kb = (kt < 4) ? kt*16 : (kt-4)*16;
        #pragma unroll
        for (int k = 0; k < 16; ++k){
            float a[8], bb[8];
            #pragma unroll
            for (int i = 0; i < 8; ++i) a[i] = Abase[(tm*8+i)*65 + kb + k];
            float4 b0 = *(const float4*)&sBt[k][tn*8];
            float4 b1 = *(const float4*)&sBt[k][tn*8+4];
            bb[0]=b0.x; bb[1]=b0.y; bb[2]=b0.z; bb[3]=b0.w;
            bb[4]=b1.x; bb[5]=b1.y; bb[6]=b1.z; bb[7]=b1.w;
            #pragma unroll
            for (int i = 0; i < 8; ++i)
                #pragma unroll
                for (int j = 0; j < 8; ++j)
                    acc[i][j] += a[i]*bb[j];
        }
        __syncthreads();
    }

    // epilogue: + D*x, * silu(z)
    float Dh = Dp[h];
    #pragma unroll
    for (int i = 0; i < 8; ++i){
        int t = t0 + tm*8 + i;
        int row = b*SEQ + t;
        size_t off = (size_t)row*D_INNER + h*D_HEAD + tn*8;
        ushort8v xv = *(const ushort8v*)((const unsigned short*)xs + off);
        float4 z0 = *(const float4*)(zbuf + off);
        float4 z1 = *(const float4*)(zbuf + off + 4);
        float zf[8] = {z0.x,z0.y,z0.z,z0.w,z1.x,z1.y,z1.z,z1.w};
        float o[8];
        #pragma unroll
        for (int j = 0; j < 8; ++j){
            float val = acc[i][j] + Dh * bf2f(xv[j]);
            o[j] = val * silu_f(zf[j]);
        }
        *(float4*)(y + off)     = make_float4(o[0],o[1],o[2],o[3]);
        *(float4*)(y + off + 4) = make_float4(o[4],o[5],o[6],o[7]);
    }
}

// ---------------- launch ----------------
extern "C" void kernel_launch(void* const* d_in, const int* in_sizes, int n_in,
                              void* d_out, int out_size, void* d_ws, size_t ws_size,
                              hipStream_t stream){
    const float* x      = (const float*)d_in[0];
    const float* norm_w = (const float*)d_in[1];
    const float* in_w   = (const float*)d_in[2];
    const float* conv_w = (const float*)d_in[3];
    const float* conv_b = (const float*)d_in[4];
    const float* A_log  = (const float*)d_in[5];
    const float* B_w    = (const float*)d_in[6];
    const float* C_w    = (const float*)d_in[7];
    const float* dt_w   = (const float*)d_in[8];
    const float* dt_b   = (const float*)d_in[9];
    const float* Dp     = (const float*)d_in[10];
    const float* out_w  = (const float*)d_in[11];
    float* out = (float*)d_out;

    char* ws = (char*)d_ws;
    float*          xpre = (float*)(ws);                         // [0,32MB) also y
    float*          y    = xpre;
    float*          zbuf = (float*)(ws + 33554432ull);           // [32,64)
    __hip_bfloat16* xs   = (__hip_bfloat16*)(ws + 67108864ull);  // [64,80) bf16
    __hip_bfloat16* Bm   = (__hip_bfloat16*)(ws + 83886080ull);  // [80,84)
    __hip_bfloat16* Cm   = (__hip_bfloat16*)(ws + 88080384ull);  // [84,88)
    float*          dtb  = (float*)(ws + 92274688ull);           // 128KB
    float*          cums = (float*)(ws + 92405760ull);           // 128KB
    float*          HS   = (float*)(ws + 92536832ull);           // 32MB  [~88.25, ~120.25)
    float*          xn   = (float*)(ws + 92536832ull);           // alias: dead before HS used

    rmsnorm_kernel<<<ROWS, 256, 0, stream>>>(x, norm_w, xn);

    gemm_nt_kernel<false><<<dim3(16,32), 256, 0, stream>>>(xn, in_w, xpre, nullptr,
        ROWS, D_INNER, D_MODEL, D_MODEL, D_MODEL, D_INNER);
    gemm_nt_kernel<false><<<dim3(16,32), 256, 0, stream>>>(xn, in_w + (size_t)D_INNER*D_MODEL, zbuf, nullptr,
        ROWS, D_INNER, D_MODEL, D_MODEL, D_MODEL, D_INNER);

    conv_silu_kernel<<<(ROWS*D_INNER)/256, 256, 0, stream>>>(xpre, conv_w, conv_b, xs);

    dt_kernel<<<ROWS, 256, 0, stream>>>(xs, dt_w, dt_b, dtb);

    gemm_bf16a_kernel<<<dim3(4,32), 256, 0, stream>>>(xs, B_w, Bm,
        ROWS, 512, D_INNER, D_INNER, D_INNER, 512);
    gemm_bf16a_kernel<<<dim3(4,32), 256, 0, stream>>>(xs, C_w, Cm,
        ROWS, 512, D_INNER, D_INNER, D_INNER, 512);

    cums_kernel<<<dim3(NCHUNK, N_HEADS, BATCH), 64, 0, stream>>>(dtb, A_log, cums);

    chunk_state_kernel<<<dim3(NCHUNK, N_HEADS, BATCH), 256, 0, stream>>>(xs, Bm, dtb, cums, HS);

    state_pass_kernel<<<BATCH*N_HEADS, 256, 0, stream>>>(cums, HS);

    chunk_out_kernel<<<dim3(NCHUNK, N_HEADS, BATCH), 256, 0, stream>>>(xs, zbuf, Bm, Cm, dtb, cums, HS, Dp, y);

    gemm_nt_kernel<true><<<dim3(8,32), 256, 0, stream>>>(y, out_w, out, x,
        ROWS, D_MODEL, D_INNER, D_INNER, D_INNER, D_MODEL);
}

// Round 3
// 369.925 us; speedup vs baseline: 7.1119x; 4.1426x over previous
//
#include <hip/hip_runtime.h>
#include <hip/hip_bf16.h>
#include <math.h>

#define D_MODEL 1024
#define D_STATE 64
#define D_CONV  4
#define D_INNER 2048
#define N_HEADS 8
#define D_HEAD  256
#define BATCH   2
#define SEQ     2048
#define ROWS    (BATCH*SEQ)   /* 4096 */
#define NCHUNK  32            /* SEQ/64 */
#define EPS     1e-6f

typedef __attribute__((ext_vector_type(4))) unsigned short ushort4v;
typedef __attribute__((ext_vector_type(8))) unsigned short ushort8v;
typedef __attribute__((ext_vector_type(8))) short short8v;
typedef __attribute__((ext_vector_type(4))) float f32x4;

__device__ __forceinline__ float silu_f(float x){ return x / (1.0f + __expf(-x)); }
__device__ __forceinline__ float softplus_f(float x){ return (x > 20.0f) ? x : log1pf(__expf(x)); }
__device__ __forceinline__ float bf2f(unsigned short u){
    union { unsigned int i; float f; } v; v.i = ((unsigned int)u) << 16; return v.f;
}
__device__ __forceinline__ unsigned short f2bf_bits(float f){
    __hip_bfloat16 h = __float2bfloat16(f);
    return *(unsigned short*)&h;
}
__device__ __forceinline__ void gload_lds16(const void* g, void* l){
    __builtin_amdgcn_global_load_lds((const __attribute__((address_space(1))) void*)g,
                                     (__attribute__((address_space(3))) void*)l, 16, 0, 0);
}

// ---------------- fp32 -> bf16 convert (weights) ----------------
__global__ __launch_bounds__(256) void f2bf_kernel(const float* __restrict__ src,
                                                   unsigned short* __restrict__ dst, int n4){
    int i = blockIdx.x * 256 + threadIdx.x;
    if (i < n4){
        float4 v = ((const float4*)src)[i];
        ushort4v o;
        o[0] = f2bf_bits(v.x); o[1] = f2bf_bits(v.y);
        o[2] = f2bf_bits(v.z); o[3] = f2bf_bits(v.w);
        ((ushort4v*)dst)[i] = o;
    }
}

// ---------------- RMSNorm -> bf16 ----------------
__global__ __launch_bounds__(256) void rmsnorm_kernel(const float* __restrict__ x,
                                                      const float* __restrict__ w,
                                                      unsigned short* __restrict__ xn){
    int row = blockIdx.x;
    int tid = threadIdx.x;
    const float4* xr = (const float4*)(x + (size_t)row * D_MODEL);
    float4 a = xr[tid];
    float ss = a.x*a.x + a.y*a.y + a.z*a.z + a.w*a.w;
    #pragma unroll
    for (int i = 1; i < 64; i <<= 1) ss += __shfl_xor(ss, i);
    __shared__ float red[4];
    int lane = tid & 63, wid = tid >> 6;
    if (lane == 0) red[wid] = ss;
    __syncthreads();
    float tot = red[0] + red[1] + red[2] + red[3];
    float scale = rsqrtf(tot * (1.0f / D_MODEL) + EPS);
    float4 wv = ((const float4*)w)[tid];
    ushort4v o;
    o[0] = f2bf_bits(a.x * scale * wv.x);
    o[1] = f2bf_bits(a.y * scale * wv.y);
    o[2] = f2bf_bits(a.z * scale * wv.z);
    o[3] = f2bf_bits(a.w * scale * wv.w);
    ((ushort4v*)(xn + (size_t)row * D_MODEL))[tid] = o;
}

// ---------------- bf16 MFMA NT GEMM: C[M][N] = A[M][K] @ W[N][K]^T ----------------
// 128x128 tile, BK=32, 256 threads (4 waves, 2x2 of 64x64), m97 structure.
// MODE 0: bf16 out; MODE 2: f32 out + f32 residual add.
template<int MODE>
__global__ __launch_bounds__(256) void gemm_mfma(const unsigned short* __restrict__ A,
                                                 const unsigned short* __restrict__ W,
                                                 void* __restrict__ Cout,
                                                 const float* __restrict__ resid,
                                                 int M, int N, int K){
    __shared__ unsigned short As[128*32];
    __shared__ unsigned short Bs[128*32];
    int tid = threadIdx.x;
    int m0 = blockIdx.y * 128, n0 = blockIdx.x * 128;
    int lane = tid & 63;
    int wave = tid >> 6;
    int wr = wave >> 1, wc = wave & 1;
    f32x4 acc[4][4];
    #pragma unroll
    for (int i = 0; i < 4; ++i)
        #pragma unroll
        for (int j = 0; j < 4; ++j) acc[i][j] = (f32x4){0.f,0.f,0.f,0.f};

    int srow = tid >> 2;            // 0..63
    int scol = (tid & 3) * 8;
    const unsigned short* aS0 = A + (size_t)(m0 + srow)*K + scol;
    const unsigned short* aS1 = aS0 + (size_t)64*K;
    const unsigned short* bS0 = W + (size_t)(n0 + srow)*K + scol;
    const unsigned short* bS1 = bS0 + (size_t)64*K;
    unsigned short* aD0 = As + (size_t)tid*8;
    unsigned short* aD1 = As + (size_t)(tid+256)*8;
    unsigned short* bD0 = Bs + (size_t)tid*8;
    unsigned short* bD1 = Bs + (size_t)(tid+256)*8;

    int frow = lane & 15;
    int fk   = (lane >> 4) * 8;

    for (int k0 = 0; k0 < K; k0 += 32){
        gload_lds16(aS0 + k0, aD0);
        gload_lds16(aS1 + k0, aD1);
        gload_lds16(bS0 + k0, bD0);
        gload_lds16(bS1 + k0, bD1);
        __syncthreads();
        short8v af[4], bf[4];
        #pragma unroll
        for (int m = 0; m < 4; ++m)
            af[m] = *(const short8v*)(As + (size_t)(wr*64 + m*16 + frow)*32 + fk);
        #pragma unroll
        for (int n = 0; n < 4; ++n)
            bf[n] = *(const short8v*)(Bs + (size_t)(wc*64 + n*16 + frow)*32 + fk);
        #pragma unroll
        for (int m = 0; m < 4; ++m)
            #pragma unroll
            for (int n = 0; n < 4; ++n)
                acc[m][n] = __builtin_amdgcn_mfma_f32_16x16x32_bf16(af[m], bf[n], acc[m][n], 0, 0, 0);
        __syncthreads();
    }

    int rrow = (lane >> 4) * 4;
    int rcol = lane & 15;
    #pragma unroll
    for (int m = 0; m < 4; ++m){
        #pragma unroll
        for (int n = 0; n < 4; ++n){
            int cc = n0 + wc*64 + n*16 + rcol;
            #pragma unroll
            for (int i = 0; i < 4; ++i){
                int rr = m0 + wr*64 + m*16 + rrow + i;
                if (MODE == 0){
                    ((unsigned short*)Cout)[(size_t)rr*N + cc] = f2bf_bits(acc[m][n][i]);
                } else {
                    ((float*)Cout)[(size_t)rr*N + cc] = acc[m][n][i] + resid[(size_t)rr*N + cc];
                }
            }
        }
    }
}

// ---------------- depthwise causal conv (K=4) + SiLU, bf16 in/out ----------------
__global__ __launch_bounds__(256) void conv_silu_kernel(const unsigned short* __restrict__ xp,
                                                        const float* __restrict__ cw,
                                                        const float* __restrict__ cb,
                                                        unsigned short* __restrict__ xs){
    int idx = blockIdx.x * 256 + threadIdx.x;
    int c = idx & (D_INNER - 1);
    int r = idx >> 11;
    int t = r & (SEQ - 1);
    float acc = cb[c];
    #pragma unroll
    for (int j = 0; j < 4; ++j){
        int tt = t - 3 + j;
        if (tt >= 0) acc += bf2f(xp[(size_t)(r - 3 + j)*D_INNER + c]) * cw[c*4 + j];
    }
    xs[idx] = f2bf_bits(silu_f(acc));
}

// ---------------- dt = softplus(xs @ dt_w^T + dt_b) ----------------
__global__ __launch_bounds__(256) void dt_kernel(const unsigned short* __restrict__ xs,
                                                 const float* __restrict__ dt_w,
                                                 const float* __restrict__ dt_b,
                                                 float* __restrict__ dt){
    __shared__ float sx[D_INNER];
    __shared__ float red[4];
    int row = blockIdx.x, tid = threadIdx.x;
    ushort8v v = ((const ushort8v*)(xs + (size_t)row * D_INNER))[tid];
    #pragma unroll
    for (int j = 0; j < 8; ++j) sx[tid*8 + j] = bf2f(v[j]);
    __syncthreads();
    int lane = tid & 63, wid = tid >> 6;
    for (int h = 0; h < N_HEADS; ++h){
        float p = 0.f;
        for (int k = tid; k < D_INNER; k += 256) p += sx[k] * dt_w[h*D_INNER + k];
        #pragma unroll
        for (int i = 1; i < 64; i <<= 1) p += __shfl_xor(p, i);
        if (lane == 0) red[wid] = p;
        __syncthreads();
        if (tid == 0){
            float s = red[0]+red[1]+red[2]+red[3] + dt_b[h];
            dt[(size_t)row*N_HEADS + h] = softplus_f(s);
        }
        __syncthreads();
    }
}

// ---------------- per-chunk inclusive prefix of a_t = dt_t * A_h ----------------
__global__ __launch_bounds__(64) void cums_kernel(const float* __restrict__ dtb,
                                                  const float* __restrict__ A_log,
                                                  float* __restrict__ cums){
    int c = blockIdx.x, h = blockIdx.y, b = blockIdx.z;
    int lane = threadIdx.x;
    int t = c*64 + lane;
    float Ah = -__expf(A_log[h]);
    float a = dtb[(size_t)(b*SEQ + t)*N_HEADS + h] * Ah;
    #pragma unroll
    for (int i = 1; i < 64; i <<= 1){
        float v = __shfl_up(a, i);
        if (lane >= i) a += v;
    }
    cums[((size_t)(b*N_HEADS + h))*SEQ + t] = a;
}

// ---------------- per-chunk state contribution: S = (B*decay)^T @ (dt*X) ----------------
__global__ __launch_bounds__(256) void chunk_state_kernel(const unsigned short* __restrict__ xs,
                                                          const unsigned short* __restrict__ Bm,
                                                          const float* __restrict__ dtb,
                                                          const float* __restrict__ cums,
                                                          float* __restrict__ HS){
    int c = blockIdx.x, h = blockIdx.y, b = blockIdx.z;
    int tid = threadIdx.x;
    int bh = b*N_HEADS + h;
    int t0 = c*64;
    float cumtot = cums[(size_t)bh*SEQ + t0 + 63];
    __shared__ float sB[16][65];
    __shared__ float sX[16][256];
    float acc[8][8];
    #pragma unroll
    for (int i = 0; i < 8; ++i)
        #pragma unroll
        for (int j = 0; j < 8; ++j) acc[i][j] = 0.f;
    int tm = tid >> 5, tn = tid & 31;
    int trL = tid >> 4, seg = tid & 15;

    for (int kt = 0; kt < 4; ++kt){
        int t = t0 + kt*16 + trL;
        int row = b*SEQ + t;
        float wdecay = __expf(cumtot - cums[(size_t)bh*SEQ + t]);
        ushort4v bv = *(const ushort4v*)(Bm + (size_t)row*512 + h*64 + seg*4);
        sB[trL][seg*4+0] = bf2f(bv[0])*wdecay;
        sB[trL][seg*4+1] = bf2f(bv[1])*wdecay;
        sB[trL][seg*4+2] = bf2f(bv[2])*wdecay;
        sB[trL][seg*4+3] = bf2f(bv[3])*wdecay;
        float dtv = dtb[(size_t)row*N_HEADS + h];
        const unsigned short* xp = xs + (size_t)row*D_INNER + h*D_HEAD + seg*16;
        ushort8v x0 = ((const ushort8v*)xp)[0];
        ushort8v x1 = ((const ushort8v*)xp)[1];
        #pragma unroll
        for (int j = 0; j < 8; ++j){
            sX[trL][seg*16 + j]     = bf2f(x0[j])*dtv;
            sX[trL][seg*16 + 8 + j] = bf2f(x1[j])*dtv;
        }
        __syncthreads();
        #pragma unroll
        for (int k = 0; k < 16; ++k){
            float a[8], bb[8];
            #pragma unroll
            for (int i = 0; i < 8; ++i) a[i] = sB[k][tm*8+i];
            float4 b0 = *(const float4*)&sX[k][tn*8];
            float4 b1 = *(const float4*)&sX[k][tn*8+4];
            bb[0]=b0.x; bb[1]=b0.y; bb[2]=b0.z; bb[3]=b0.w;
            bb[4]=b1.x; bb[5]=b1.y; bb[6]=b1.z; bb[7]=b1.w;
            #pragma unroll
            for (int i = 0; i < 8; ++i)
                #pragma unroll
                for (int j = 0; j < 8; ++j)
                    acc[i][j] += a[i]*bb[j];
        }
        __syncthreads();
    }
    float* out = HS + ((size_t)bh*NCHUNK + c)*16384;
    #pragma unroll
    for (int i = 0; i < 8; ++i){
        float* orow = out + (tm*8+i)*256 + tn*8;
        *(float4*)orow     = make_float4(acc[i][0],acc[i][1],acc[i][2],acc[i][3]);
        *(float4*)(orow+4) = make_float4(acc[i][4],acc[i][5],acc[i][6],acc[i][7]);
    }
}

// ---------------- chunk-recurrence over states: HS[c] := H_start(c), parallel over (bh,n,d) ----------------
__global__ __launch_bounds__(256) void state_pass_kernel(const float* __restrict__ cums,
                                                         float* __restrict__ HS){
    int n  = blockIdx.x;     // 0..63
    int bh = blockIdx.y;     // 0..15
    int d  = threadIdx.x;    // 0..255
    float H = 0.f;
    float* p = HS + ((size_t)bh*NCHUNK)*16384 + (size_t)n*256 + d;
    const float* cp = cums + (size_t)bh*SEQ + 63;
    for (int c = 0; c < NCHUNK; ++c){
        float Pc = __expf(cp[(size_t)c*64]);
        float s = *p;
        *p = H;
        H = fmaf(Pc, H, s);
        p += 16384;
    }
}

// ---------------- per-chunk output ----------------
__global__ __launch_bounds__(256) void chunk_out_kernel(const unsigned short* __restrict__ xs,
                                                        const unsigned short* __restrict__ zbuf,
                                                        const unsigned short* __restrict__ Bm,
                                                        const unsigned short* __restrict__ Cm,
                                                        const float* __restrict__ dtb,
                                                        const float* __restrict__ cums,
                                                        const float* __restrict__ HS,
                                                        const float* __restrict__ Dp,
                                                        unsigned short* __restrict__ y){
    int c = blockIdx.x, h = blockIdx.y, b = blockIdx.z;
    int tid = threadIdx.x;
    int bh = b*N_HEADS + h;
    int t0 = c*64;
    __shared__ float sC[64][65];
    __shared__ float sB[64][65];   // later reused as sBt[16][256]
    __shared__ float sW[64][65];
    __shared__ float scum[64];
    float (*sBt)[256] = reinterpret_cast<float(*)[256]>(&sB[0][0]);

    int trL = tid >> 2, segL = tid & 3;
    {
        int row = b*SEQ + t0 + trL;
        const unsigned short* cp = Cm + (size_t)row*512 + h*64 + segL*16;
        const unsigned short* bp = Bm + (size_t)row*512 + h*64 + segL*16;
        ushort8v c0 = ((const ushort8v*)cp)[0], c1 = ((const ushort8v*)cp)[1];
        ushort8v b0 = ((const ushort8v*)bp)[0], b1 = ((const ushort8v*)bp)[1];
        #pragma unroll
        for (int j = 0; j < 8; ++j){
            sC[trL][segL*16 + j]     = bf2f(c0[j]);
            sC[trL][segL*16 + 8 + j] = bf2f(c1[j]);
            sB[trL][segL*16 + j]     = bf2f(b0[j]);
            sB[trL][segL*16 + 8 + j] = bf2f(b1[j]);
        }
        if (tid < 64) scum[tid] = cums[(size_t)bh*SEQ + t0 + tid];
    }
    __syncthreads();

    int tG = (tid >> 4) * 4, sG = (tid & 15) * 4;
    float g[4][4];
    #pragma unroll
    for (int i = 0; i < 4; ++i)
        #pragma unroll
        for (int j = 0; j < 4; ++j) g[i][j] = 0.f;
    for (int n = 0; n < 64; ++n){
        float a[4], bb[4];
        #pragma unroll
        for (int i = 0; i < 4; ++i) a[i] = sC[tG+i][n];
        #pragma unroll
        for (int j = 0; j < 4; ++j) bb[j] = sB[sG+j][n];
        #pragma unroll
        for (int i = 0; i < 4; ++i)
            #pragma unroll
            for (int j = 0; j < 4; ++j) g[i][j] += a[i]*bb[j];
    }
    #pragma unroll
    for (int i = 0; i < 4; ++i){
        int t = tG + i;
        #pragma unroll
        for (int j = 0; j < 4; ++j){
            int s = sG + j;
            sW[t][s] = (s <= t) ? __expf(scum[t]-scum[s]) * g[i][j] : 0.f;
        }
    }
    __syncthreads();
    {
        float ef = __expf(scum[trL]);
        #pragma unroll
        for (int j = 0; j < 16; ++j) sC[trL][segL*16 + j] *= ef;
    }
    __syncthreads();

    float acc[8][8];
    #pragma unroll
    for (int i = 0; i < 8; ++i)
        #pragma unroll
        for (int j = 0; j < 8; ++j) acc[i][j] = 0.f;
    int tm = tid >> 5, tn = tid & 31;
    int trX = tid >> 4, seg = tid & 15;
    size_t hsbase = ((size_t)bh*NCHUNK + c)*16384;

    for (int kt = 0; kt < 8; ++kt){
        if (kt < 4){
            int t = t0 + kt*16 + trX;
            int row = b*SEQ + t;
            float dtv = dtb[(size_t)row*N_HEADS + h];
            const unsigned short* xp = xs + (size_t)row*D_INNER + h*D_HEAD + seg*16;
            ushort8v x0 = ((const ushort8v*)xp)[0];
            ushort8v x1 = ((const ushort8v*)xp)[1];
            #pragma unroll
            for (int j = 0; j < 8; ++j){
                sBt[trX][seg*16 + j]     = bf2f(x0[j])*dtv;
                sBt[trX][seg*16 + 8 + j] = bf2f(x1[j])*dtv;
            }
        } else {
            int n = (kt-4)*16 + trX;
            const float* hp = HS + hsbase + (size_t)n*256 + seg*16;
            float4 h0 = ((const float4*)hp)[0];
            float4 h1 = ((const float4*)hp)[1];
            float4 h2 = ((const float4*)hp)[2];
            float4 h3 = ((const float4*)hp)[3];
            *(float4*)&sBt[trX][seg*16+0]  = h0;
            *(float4*)&sBt[trX][seg*16+4]  = h1;
            *(float4*)&sBt[trX][seg*16+8]  = h2;
            *(float4*)&sBt[trX][seg*16+12] = h3;
        }
        __syncthreads();
        const float* Abase = (kt < 4) ? &sW[0][0] : &sC[0][0];
        int kb = (kt < 4) ? kt*16 : (kt-4)*16;
        #pragma unroll
        for (int k = 0; k < 16; ++k){
            float a[8], bb[8];
            #pragma unroll
            for (int i = 0; i < 8; ++i) a[i] = Abase[(tm*8+i)*65 + kb + k];
            float4 b0 = *(const float4*)&sBt[k][tn*8];
            float4 b1 = *(const float4*)&sBt[k][tn*8+4];
            bb[0]=b0.x; bb[1]=b0.y; bb[2]=b0.z; bb[3]=b0.w;
            bb[4]=b1.x; bb[5]=b1.y; bb[6]=b1.z; bb[7]=b1.w;
            #pragma unroll
            for (int i = 0; i < 8; ++i)
                #pragma unroll
                for (int j = 0; j < 8; ++j)
                    acc[i][j] += a[i]*bb[j];
        }
        __syncthreads();
    }

    float Dh = Dp[h];
    #pragma unroll
    for (int i = 0; i < 8; ++i){
        int t = t0 + tm*8 + i;
        int row = b*SEQ + t;
        size_t off = (size_t)row*D_INNER + h*D_HEAD + tn*8;
        ushort8v xv = *(const ushort8v*)(xs + off);
        ushort8v zv = *(const ushort8v*)(zbuf + off);
        ushort8v o;
        #pragma unroll
        for (int j = 0; j < 8; ++j){
            float val = acc[i][j] + Dh * bf2f(xv[j]);
            o[j] = f2bf_bits(val * silu_f(bf2f(zv[j])));
        }
        *(ushort8v*)(y + off) = o;
    }
}

// ---------------- launch ----------------
extern "C" void kernel_launch(void* const* d_in, const int* in_sizes, int n_in,
                              void* d_out, int out_size, void* d_ws, size_t ws_size,
                              hipStream_t stream){
    const float* x      = (const float*)d_in[0];
    const float* norm_w = (const float*)d_in[1];
    const float* in_w   = (const float*)d_in[2];
    const float* conv_w = (const float*)d_in[3];
    const float* conv_b = (const float*)d_in[4];
    const float* A_log  = (const float*)d_in[5];
    const float* B_w    = (const float*)d_in[6];
    const float* C_w    = (const float*)d_in[7];
    const float* dt_w   = (const float*)d_in[8];
    const float* dt_b   = (const float*)d_in[9];
    const float* Dp     = (const float*)d_in[10];
    const float* out_w  = (const float*)d_in[11];
    float* out = (float*)d_out;

    char* ws = (char*)d_ws;
    const size_t MB = 1048576ull;
    unsigned short* xn_bf   = (unsigned short*)(ws);             // 8 MB
    unsigned short* inw_bf  = (unsigned short*)(ws + 8*MB);      // 8 MB
    unsigned short* outw_bf = (unsigned short*)(ws + 16*MB);     // 4 MB
    unsigned short* Bw_bf   = (unsigned short*)(ws + 20*MB);     // 2 MB
    unsigned short* Cw_bf   = (unsigned short*)(ws + 22*MB);     // 2 MB
    unsigned short* xpre_bf = (unsigned short*)(ws + 24*MB);     // 16 MB (reused as y)
    unsigned short* y_bf    = xpre_bf;
    unsigned short* z_bf    = (unsigned short*)(ws + 40*MB);     // 16 MB
    unsigned short* xs_bf   = (unsigned short*)(ws + 56*MB);     // 16 MB
    unsigned short* Bm      = (unsigned short*)(ws + 72*MB);     // 4 MB
    unsigned short* Cm      = (unsigned short*)(ws + 76*MB);     // 4 MB
    float*          dtb     = (float*)(ws + 80*MB);              // 128 KB
    float*          cums    = (float*)(ws + 80*MB + 131072);     // 128 KB
    float*          HS      = (float*)(ws + 81*MB);              // 32 MB -> ends 113 MB

    // weight conversions
    f2bf_kernel<<<(D_INNER*2*D_MODEL/4 + 255)/256, 256, 0, stream>>>(in_w,  inw_bf,  D_INNER*2*D_MODEL/4);
    f2bf_kernel<<<(D_MODEL*D_INNER/4 + 255)/256, 256, 0, stream>>>(out_w, outw_bf, D_MODEL*D_INNER/4);
    f2bf_kernel<<<(512*D_INNER/4 + 255)/256, 256, 0, stream>>>(B_w, Bw_bf, 512*D_INNER/4);
    f2bf_kernel<<<(512*D_INNER/4 + 255)/256, 256, 0, stream>>>(C_w, Cw_bf, 512*D_INNER/4);

    rmsnorm_kernel<<<ROWS, 256, 0, stream>>>(x, norm_w, xn_bf);

    // in_proj halves (bf16 MFMA)
    gemm_mfma<0><<<dim3(16,32), 256, 0, stream>>>(xn_bf, inw_bf, xpre_bf, nullptr,
        ROWS, D_INNER, D_MODEL);
    gemm_mfma<0><<<dim3(16,32), 256, 0, stream>>>(xn_bf, inw_bf + (size_t)D_INNER*D_MODEL, z_bf, nullptr,
        ROWS, D_INNER, D_MODEL);

    conv_silu_kernel<<<(ROWS*D_INNER)/256, 256, 0, stream>>>(xpre_bf, conv_w, conv_b, xs_bf);

    dt_kernel<<<ROWS, 256, 0, stream>>>(xs_bf, dt_w, dt_b, dtb);

    gemm_mfma<0><<<dim3(4,32), 256, 0, stream>>>(xs_bf, Bw_bf, Bm, nullptr,
        ROWS, 512, D_INNER);
    gemm_mfma<0><<<dim3(4,32), 256, 0, stream>>>(xs_bf, Cw_bf, Cm, nullptr,
        ROWS, 512, D_INNER);

    cums_kernel<<<dim3(NCHUNK, N_HEADS, BATCH), 64, 0, stream>>>(dtb, A_log, cums);

    chunk_state_kernel<<<dim3(NCHUNK, N_HEADS, BATCH), 256, 0, stream>>>(xs_bf, Bm, dtb, cums, HS);

    state_pass_kernel<<<dim3(64, BATCH*N_HEADS), 256, 0, stream>>>(cums, HS);

    chunk_out_kernel<<<dim3(NCHUNK, N_HEADS, BATCH), 256, 0, stream>>>(xs_bf, z_bf, Bm, Cm, dtb, cums, HS, Dp, y_bf);

    // out = x + y @ out_w^T  (bf16 MFMA, f32 out + residual)
    gemm_mfma<2><<<dim3(8,32), 256, 0, stream>>>(y_bf, outw_bf, out, x,
        ROWS, D_MODEL, D_INNER);
}

// Round 4
// 343.033 us; speedup vs baseline: 7.6694x; 1.0784x over previous
//
#include <hip/hip_runtime.h>
#include <hip/hip_bf16.h>
#include <math.h>

#define D_MODEL 1024
#define D_STATE 64
#define D_CONV  4
#define D_INNER 2048
#define N_HEADS 8
#define D_HEAD  256
#define BATCH   2
#define SEQ     2048
#define ROWS    (BATCH*SEQ)   /* 4096 */
#define NCHUNK  32            /* SEQ/64 */
#define EPS     1e-6f

typedef __attribute__((ext_vector_type(4))) unsigned short ushort4v;
typedef __attribute__((ext_vector_type(8))) unsigned short ushort8v;
typedef __attribute__((ext_vector_type(8))) short short8v;
typedef __attribute__((ext_vector_type(4))) float f32x4;

__device__ __forceinline__ float silu_f(float x){ return x / (1.0f + __expf(-x)); }
__device__ __forceinline__ float softplus_f(float x){ return (x > 20.0f) ? x : log1pf(__expf(x)); }
__device__ __forceinline__ float bf2f(unsigned short u){
    union { unsigned int i; float f; } v; v.i = ((unsigned int)u) << 16; return v.f;
}
__device__ __forceinline__ unsigned short f2bf_bits(float f){
    __hip_bfloat16 h = __float2bfloat16(f);
    return *(unsigned short*)&h;
}
__device__ __forceinline__ void gload_lds16(const void* g, void* l){
    __builtin_amdgcn_global_load_lds((const __attribute__((address_space(1))) void*)g,
                                     (__attribute__((address_space(3))) void*)l, 16, 0, 0);
}

// ---------------- fp32 -> bf16 convert (weights) ----------------
__global__ __launch_bounds__(256) void f2bf_kernel(const float* __restrict__ src,
                                                   unsigned short* __restrict__ dst, int n4){
    int i = blockIdx.x * 256 + threadIdx.x;
    if (i < n4){
        float4 v = ((const float4*)src)[i];
        ushort4v o;
        o[0] = f2bf_bits(v.x); o[1] = f2bf_bits(v.y);
        o[2] = f2bf_bits(v.z); o[3] = f2bf_bits(v.w);
        ((ushort4v*)dst)[i] = o;
    }
}

// ---------------- RMSNorm -> bf16 ----------------
__global__ __launch_bounds__(256) void rmsnorm_kernel(const float* __restrict__ x,
                                                      const float* __restrict__ w,
                                                      unsigned short* __restrict__ xn){
    int row = blockIdx.x;
    int tid = threadIdx.x;
    const float4* xr = (const float4*)(x + (size_t)row * D_MODEL);
    float4 a = xr[tid];
    float ss = a.x*a.x + a.y*a.y + a.z*a.z + a.w*a.w;
    #pragma unroll
    for (int i = 1; i < 64; i <<= 1) ss += __shfl_xor(ss, i);
    __shared__ float red[4];
    int lane = tid & 63, wid = tid >> 6;
    if (lane == 0) red[wid] = ss;
    __syncthreads();
    float tot = red[0] + red[1] + red[2] + red[3];
    float scale = rsqrtf(tot * (1.0f / D_MODEL) + EPS);
    float4 wv = ((const float4*)w)[tid];
    ushort4v o;
    o[0] = f2bf_bits(a.x * scale * wv.x);
    o[1] = f2bf_bits(a.y * scale * wv.y);
    o[2] = f2bf_bits(a.z * scale * wv.z);
    o[3] = f2bf_bits(a.w * scale * wv.w);
    ((ushort4v*)(xn + (size_t)row * D_MODEL))[tid] = o;
}

// ---------------- bf16 MFMA NT GEMM (projections) ----------------
template<int MODE>
__global__ __launch_bounds__(256) void gemm_mfma(const unsigned short* __restrict__ A,
                                                 const unsigned short* __restrict__ W,
                                                 void* __restrict__ Cout,
                                                 const float* __restrict__ resid,
                                                 int M, int N, int K){
    __shared__ unsigned short As[128*32];
    __shared__ unsigned short Bs[128*32];
    int tid = threadIdx.x;
    int m0 = blockIdx.y * 128, n0 = blockIdx.x * 128;
    int lane = tid & 63;
    int wave = tid >> 6;
    int wr = wave >> 1, wc = wave & 1;
    f32x4 acc[4][4];
    #pragma unroll
    for (int i = 0; i < 4; ++i)
        #pragma unroll
        for (int j = 0; j < 4; ++j) acc[i][j] = (f32x4){0.f,0.f,0.f,0.f};

    int srow = tid >> 2;
    int scol = (tid & 3) * 8;
    const unsigned short* aS0 = A + (size_t)(m0 + srow)*K + scol;
    const unsigned short* aS1 = aS0 + (size_t)64*K;
    const unsigned short* bS0 = W + (size_t)(n0 + srow)*K + scol;
    const unsigned short* bS1 = bS0 + (size_t)64*K;
    unsigned short* aD0 = As + (size_t)tid*8;
    unsigned short* aD1 = As + (size_t)(tid+256)*8;
    unsigned short* bD0 = Bs + (size_t)tid*8;
    unsigned short* bD1 = Bs + (size_t)(tid+256)*8;

    int frow = lane & 15;
    int fk   = (lane >> 4) * 8;

    for (int k0 = 0; k0 < K; k0 += 32){
        gload_lds16(aS0 + k0, aD0);
        gload_lds16(aS1 + k0, aD1);
        gload_lds16(bS0 + k0, bD0);
        gload_lds16(bS1 + k0, bD1);
        __syncthreads();
        short8v af[4], bf[4];
        #pragma unroll
        for (int m = 0; m < 4; ++m)
            af[m] = *(const short8v*)(As + (size_t)(wr*64 + m*16 + frow)*32 + fk);
        #pragma unroll
        for (int n = 0; n < 4; ++n)
            bf[n] = *(const short8v*)(Bs + (size_t)(wc*64 + n*16 + frow)*32 + fk);
        #pragma unroll
        for (int m = 0; m < 4; ++m)
            #pragma unroll
            for (int n = 0; n < 4; ++n)
                acc[m][n] = __builtin_amdgcn_mfma_f32_16x16x32_bf16(af[m], bf[n], acc[m][n], 0, 0, 0);
        __syncthreads();
    }

    int rrow = (lane >> 4) * 4;
    int rcol = lane & 15;
    #pragma unroll
    for (int m = 0; m < 4; ++m){
        #pragma unroll
        for (int n = 0; n < 4; ++n){
            int cc = n0 + wc*64 + n*16 + rcol;
            #pragma unroll
            for (int i = 0; i < 4; ++i){
                int rr = m0 + wr*64 + m*16 + rrow + i;
                if (MODE == 0){
                    ((unsigned short*)Cout)[(size_t)rr*N + cc] = f2bf_bits(acc[m][n][i]);
                } else {
                    ((float*)Cout)[(size_t)rr*N + cc] = acc[m][n][i] + resid[(size_t)rr*N + cc];
                }
            }
        }
    }
}

// ---------------- depthwise causal conv (K=4) + SiLU, bf16 in/out ----------------
__global__ __launch_bounds__(256) void conv_silu_kernel(const unsigned short* __restrict__ xp,
                                                        const float* __restrict__ cw,
                                                        const float* __restrict__ cb,
                                                        unsigned short* __restrict__ xs){
    int idx = blockIdx.x * 256 + threadIdx.x;
    int c = idx & (D_INNER - 1);
    int r = idx >> 11;
    int t = r & (SEQ - 1);
    float acc = cb[c];
    #pragma unroll
    for (int j = 0; j < 4; ++j){
        int tt = t - 3 + j;
        if (tt >= 0) acc += bf2f(xp[(size_t)(r - 3 + j)*D_INNER + c]) * cw[c*4 + j];
    }
    xs[idx] = f2bf_bits(silu_f(acc));
}

// ---------------- dt = softplus(xs @ dt_w^T + dt_b) ----------------
__global__ __launch_bounds__(256) void dt_kernel(const unsigned short* __restrict__ xs,
                                                 const float* __restrict__ dt_w,
                                                 const float* __restrict__ dt_b,
                                                 float* __restrict__ dt){
    __shared__ float sx[D_INNER];
    __shared__ float red[4];
    int row = blockIdx.x, tid = threadIdx.x;
    ushort8v v = ((const ushort8v*)(xs + (size_t)row * D_INNER))[tid];
    #pragma unroll
    for (int j = 0; j < 8; ++j) sx[tid*8 + j] = bf2f(v[j]);
    __syncthreads();
    int lane = tid & 63, wid = tid >> 6;
    for (int h = 0; h < N_HEADS; ++h){
        float p = 0.f;
        for (int k = tid; k < D_INNER; k += 256) p += sx[k] * dt_w[h*D_INNER + k];
        #pragma unroll
        for (int i = 1; i < 64; i <<= 1) p += __shfl_xor(p, i);
        if (lane == 0) red[wid] = p;
        __syncthreads();
        if (tid == 0){
            float s = red[0]+red[1]+red[2]+red[3] + dt_b[h];
            dt[(size_t)row*N_HEADS + h] = softplus_f(s);
        }
        __syncthreads();
    }
}

// ---------------- per-chunk inclusive prefix of a_t = dt_t * A_h ----------------
__global__ __launch_bounds__(64) void cums_kernel(const float* __restrict__ dtb,
                                                  const float* __restrict__ A_log,
                                                  float* __restrict__ cums){
    int c = blockIdx.x, h = blockIdx.y, b = blockIdx.z;
    int lane = threadIdx.x;
    int t = c*64 + lane;
    float Ah = -__expf(A_log[h]);
    float a = dtb[(size_t)(b*SEQ + t)*N_HEADS + h] * Ah;
    #pragma unroll
    for (int i = 1; i < 64; i <<= 1){
        float v = __shfl_up(a, i);
        if (lane >= i) a += v;
    }
    cums[((size_t)(b*N_HEADS + h))*SEQ + t] = a;
}

// ---------------- xdT: [bh][d][t] bf16 = xs[row][h*256+d] * dt[row] transposed ----------------
__global__ __launch_bounds__(256) void xdT_kernel(const unsigned short* __restrict__ xs,
                                                  const float* __restrict__ dtb,
                                                  unsigned short* __restrict__ xdT){
    int ct = blockIdx.x, cd = blockIdx.y, bh = blockIdx.z;
    int b = bh >> 3, h = bh & 7;
    __shared__ unsigned short sT[64*68];   // [t][d], pad 68
    int tid = threadIdx.x;
    #pragma unroll
    for (int it = 0; it < 2; ++it){
        int l = tid + it*256;
        int tl = l >> 3, seg = l & 7;
        int row = b*SEQ + ct*64 + tl;
        ushort8v v = *(const ushort8v*)(xs + (size_t)row*D_INNER + h*D_HEAD + cd*64 + seg*8);
        float dtv = dtb[(size_t)row*N_HEADS + h];
        ushort4v lo, hi;
        #pragma unroll
        for (int j = 0; j < 4; ++j){
            lo[j] = f2bf_bits(bf2f(v[j]) * dtv);
            hi[j] = f2bf_bits(bf2f(v[j+4]) * dtv);
        }
        *(ushort4v*)((char*)sT + tl*136 + seg*16)     = lo;
        *(ushort4v*)((char*)sT + tl*136 + seg*16 + 8) = hi;
    }
    __syncthreads();
    #pragma unroll
    for (int it = 0; it < 2; ++it){
        int l = tid + it*256;
        int dl = l >> 3, tseg = l & 7;
        ushort8v o;
        #pragma unroll
        for (int j = 0; j < 8; ++j) o[j] = sT[(tseg*8 + j)*68 + dl];
        *(ushort8v*)(xdT + ((size_t)bh*D_HEAD + cd*64 + dl)*SEQ + ct*64 + tseg*8) = o;
    }
}

// ---------------- chunk_state (MFMA): HS[bh][c][d][n] = sum_t XdT[d][t]*Bdecay[t][n] ----------------
__global__ __launch_bounds__(256) void chunk_state_mfma(const unsigned short* __restrict__ xdT,
                                                        const unsigned short* __restrict__ Bm,
                                                        const float* __restrict__ cums,
                                                        float* __restrict__ HS){
    int c = blockIdx.x, h = blockIdx.y, b = blockIdx.z;
    int tid = threadIdx.x;
    int bh = b*N_HEADS + h;
    int t0 = c*64;
    __shared__ unsigned short sX[256*64];   // [d][t] swizzled (^((d&7)<<4) on byte)
    __shared__ unsigned short sBdT[64*72];  // [n][t] pad 72
    __shared__ float sdec[64];
    if (tid < 64)
        sdec[tid] = __expf(cums[(size_t)bh*SEQ + t0 + 63] - cums[(size_t)bh*SEQ + t0 + tid]);
    const unsigned short* xb = xdT + (size_t)bh*D_HEAD*SEQ + t0;
    #pragma unroll
    for (int it = 0; it < 8; ++it){
        int l = tid + it*256;
        int d = l >> 3, seg = l & 7;
        gload_lds16(xb + (size_t)d*SEQ + (((seg*16) ^ ((d&7)<<4)) >> 1),
                    (char*)sX + (size_t)l*16);
    }
    __syncthreads();
    #pragma unroll
    for (int it = 0; it < 2; ++it){
        int l = tid + it*256;
        int tl = l >> 3, seg = l & 7;
        ushort8v bv = *(const ushort8v*)(Bm + (size_t)(b*SEQ + t0 + tl)*512 + h*64 + seg*8);
        float dec = sdec[tl];
        #pragma unroll
        for (int j = 0; j < 8; ++j)
            sBdT[(seg*8 + j)*72 + tl] = f2bf_bits(bf2f(bv[j]) * dec);
    }
    __syncthreads();

    int lane = tid & 63, w = tid >> 6;
    int d0 = w*64;
    int fr = lane & 15, fk = (lane >> 4)*8;
    f32x4 acc[4][4];
    #pragma unroll
    for (int i = 0; i < 4; ++i)
        #pragma unroll
        for (int j = 0; j < 4; ++j) acc[i][j] = (f32x4){0.f,0.f,0.f,0.f};
    short8v af[4][2], bg[4][2];
    #pragma unroll
    for (int m = 0; m < 4; ++m)
        #pragma unroll
        for (int k = 0; k < 2; ++k){
            int d = d0 + m*16 + fr;
            af[m][k] = *(const short8v*)((const char*)sX + (size_t)d*128 + (((k*32+fk)*2) ^ ((d&7)<<4)));
        }
    #pragma unroll
    for (int n = 0; n < 4; ++n)
        #pragma unroll
        for (int k = 0; k < 2; ++k)
            bg[n][k] = *(const short8v*)(sBdT + (size_t)(n*16 + fr)*72 + k*32 + fk);
    #pragma unroll
    for (int k = 0; k < 2; ++k)
        #pragma unroll
        for (int m = 0; m < 4; ++m)
            #pragma unroll
            for (int n = 0; n < 4; ++n)
                acc[m][n] = __builtin_amdgcn_mfma_f32_16x16x32_bf16(af[m][k], bg[n][k], acc[m][n], 0, 0, 0);

    float* out = HS + ((size_t)bh*NCHUNK + c)*16384;
    int rr = (lane >> 4)*4, rc = lane & 15;
    #pragma unroll
    for (int m = 0; m < 4; ++m)
        #pragma unroll
        for (int n = 0; n < 4; ++n)
            #pragma unroll
            for (int i = 0; i < 4; ++i)
                out[(size_t)(d0 + m*16 + rr + i)*64 + n*16 + rc] = acc[m][n][i];
}

// ---------------- chunk recurrence: HS[c] := H_start(c) ----------------
__global__ __launch_bounds__(256) void state_pass_kernel(const float* __restrict__ cums,
                                                         float* __restrict__ HS){
    int e  = blockIdx.x*256 + threadIdx.x;   // 0..16383
    int bh = blockIdx.y;
    float H = 0.f;
    float* p = HS + (size_t)bh*NCHUNK*16384 + e;
    const float* cp = cums + (size_t)bh*SEQ + 63;
    for (int c = 0; c < NCHUNK; ++c){
        float Pc = __expf(cp[(size_t)c*64]);
        float s = *p;
        *p = H;
        H = fmaf(Pc, H, s);
        p += 16384;
    }
}

// ---------------- chunk_out (MFMA) ----------------
__global__ __launch_bounds__(256) void chunk_out_mfma(const unsigned short* __restrict__ xs,
                                                      const unsigned short* __restrict__ z,
                                                      const unsigned short* __restrict__ Bm,
                                                      const unsigned short* __restrict__ Cm,
                                                      const unsigned short* __restrict__ xdT,
                                                      const float* __restrict__ cums,
                                                      const float* __restrict__ HS,
                                                      const float* __restrict__ Dp,
                                                      unsigned short* __restrict__ y){
    int c = blockIdx.x, h = blockIdx.y, b = blockIdx.z;
    int tid = threadIdx.x;
    int bh = b*N_HEADS + h;
    int t0 = c*64;
    __shared__ unsigned short regA[256*64];  // phase1: [Craw|Braw] ; phase2: XdT ; phase3: HT
    __shared__ unsigned short sW[64*64];     // [t][s] swz by t
    __shared__ unsigned short sCd[64*64];    // [t][n] swz by t
    __shared__ float scum[64];
    unsigned short* Craw = regA;             // [64][64] swz by t
    unsigned short* Braw = regA + 64*64;

    if (tid < 64) scum[tid] = cums[(size_t)bh*SEQ + t0 + tid];
    #pragma unroll
    for (int it = 0; it < 2; ++it){
        int l = tid + it*256;
        int tl = l >> 3, seg = l & 7;
        size_t rowoff = (size_t)(b*SEQ + t0 + tl)*512 + h*64;
        int soff = ((seg*16) ^ ((tl&7)<<4)) >> 1;
        gload_lds16(Cm + rowoff + soff, (char*)Craw + (size_t)l*16);
        gload_lds16(Bm + rowoff + soff, (char*)Braw + (size_t)l*16);
    }
    __syncthreads();

    int lane = tid & 63, w = tid >> 6;
    int fr = lane & 15, fk = (lane >> 4)*8;
    int rr = (lane >> 4)*4, rc = lane & 15;

    // ---- G = C @ B^T (each wave a 32x32 quadrant) ----
    int wr = w >> 1, wc = w & 1;
    f32x4 g[2][2];
    #pragma unroll
    for (int i = 0; i < 2; ++i)
        #pragma unroll
        for (int j = 0; j < 2; ++j) g[i][j] = (f32x4){0.f,0.f,0.f,0.f};
    {
        short8v ca[2][2], bb[2][2];
        #pragma unroll
        for (int m = 0; m < 2; ++m)
            #pragma unroll
            for (int k = 0; k < 2; ++k){
                int t = wr*32 + m*16 + fr;
                ca[m][k] = *(const short8v*)((const char*)Craw + (size_t)t*128 + (((k*32+fk)*2) ^ ((t&7)<<4)));
            }
        #pragma unroll
        for (int n = 0; n < 2; ++n)
            #pragma unroll
            for (int k = 0; k < 2; ++k){
                int s = wc*32 + n*16 + fr;
                bb[n][k] = *(const short8v*)((const char*)Braw + (size_t)s*128 + (((k*32+fk)*2) ^ ((s&7)<<4)));
            }
        #pragma unroll
        for (int k = 0; k < 2; ++k)
            #pragma unroll
            for (int m = 0; m < 2; ++m)
                #pragma unroll
                for (int n = 0; n < 2; ++n)
                    g[m][n] = __builtin_amdgcn_mfma_f32_16x16x32_bf16(ca[m][k], bb[n][k], g[m][n], 0, 0, 0);
    }
    // W[t][s] = mask * exp(cum[t]-cum[s]) * G
    #pragma unroll
    for (int m = 0; m < 2; ++m)
        #pragma unroll
        for (int n = 0; n < 2; ++n)
            #pragma unroll
            for (int i = 0; i < 4; ++i){
                int t = wr*32 + m*16 + rr + i;
                int s = wc*32 + n*16 + rc;
                float wv = (s <= t) ? __expf(scum[t] - scum[s]) * g[m][n][i] : 0.f;
                *(unsigned short*)((char*)sW + (size_t)t*128 + ((s*2) ^ ((t&7)<<4))) = f2bf_bits(wv);
            }
    // Cd[t][n] = exp(cum[t]) * C[t][n]
    {
        int tl = tid >> 2, sg = tid & 3;
        float ef = __expf(scum[tl]);
        #pragma unroll
        for (int q = 0; q < 2; ++q){
            int off = ((sg*32 + q*16)) ^ ((tl&7)<<4);
            ushort8v cv = *(const ushort8v*)((const char*)Craw + (size_t)tl*128 + off);
            ushort8v ov;
            #pragma unroll
            for (int j = 0; j < 8; ++j) ov[j] = f2bf_bits(bf2f(cv[j]) * ef);
            *(ushort8v*)((char*)sCd + (size_t)tl*128 + off) = ov;
        }
    }
    __syncthreads();

    // ---- stage XdT[256][64] into regA ----
    const unsigned short* xb = xdT + (size_t)bh*D_HEAD*SEQ + t0;
    #pragma unroll
    for (int it = 0; it < 8; ++it){
        int l = tid + it*256;
        int d = l >> 3, seg = l & 7;
        gload_lds16(xb + (size_t)d*SEQ + (((seg*16) ^ ((d&7)<<4)) >> 1),
                    (char*)regA + (size_t)l*16);
    }
    __syncthreads();

    // ---- GEMM2a: acc[t][d] += W @ XdT^T ----
    int d0 = w*64;
    f32x4 acc[4][4];
    #pragma unroll
    for (int i = 0; i < 4; ++i)
        #pragma unroll
        for (int j = 0; j < 4; ++j) acc[i][j] = (f32x4){0.f,0.f,0.f,0.f};
    {
        short8v aw[4][2], xd[4][2];
        #pragma unroll
        for (int m = 0; m < 4; ++m)
            #pragma unroll
            for (int k = 0; k < 2; ++k){
                int t = m*16 + fr;
                aw[m][k] = *(const short8v*)((const char*)sW + (size_t)t*128 + (((k*32+fk)*2) ^ ((t&7)<<4)));
            }
        #pragma unroll
        for (int n = 0; n < 4; ++n)
            #pragma unroll
            for (int k = 0; k < 2; ++k){
                int d = d0 + n*16 + fr;
                xd[n][k] = *(const short8v*)((const char*)regA + (size_t)d*128 + (((k*32+fk)*2) ^ ((d&7)<<4)));
            }
        #pragma unroll
        for (int k = 0; k < 2; ++k)
            #pragma unroll
            for (int m = 0; m < 4; ++m)
                #pragma unroll
                for (int n = 0; n < 4; ++n)
                    acc[m][n] = __builtin_amdgcn_mfma_f32_16x16x32_bf16(aw[m][k], xd[n][k], acc[m][n], 0, 0, 0);
    }
    __syncthreads();

    // ---- stage HT[256][64] (f32 HS -> bf16) into regA ----
    size_t hsbase = ((size_t)bh*NCHUNK + c)*16384;
    {
        int q = tid >> 4, s16 = tid & 15;
        const float* hp = HS + hsbase;
        #pragma unroll
        for (int db = 0; db < 16; ++db){
            int d = db*16 + q;
            float4 hv = *(const float4*)(hp + (size_t)d*64 + s16*4);
            ushort4v ov;
            ov[0] = f2bf_bits(hv.x); ov[1] = f2bf_bits(hv.y);
            ov[2] = f2bf_bits(hv.z); ov[3] = f2bf_bits(hv.w);
            *(ushort4v*)((char*)regA + (size_t)d*128 + ((s16*8) ^ ((d&7)<<4))) = ov;
        }
    }
    __syncthreads();

    // ---- GEMM2b: acc += Cd @ HT^T ----
    {
        short8v aw[4][2], ht[4][2];
        #pragma unroll
        for (int m = 0; m < 4; ++m)
            #pragma unroll
            for (int k = 0; k < 2; ++k){
                int t = m*16 + fr;
                aw[m][k] = *(const short8v*)((const char*)sCd + (size_t)t*128 + (((k*32+fk)*2) ^ ((t&7)<<4)));
            }
        #pragma unroll
        for (int n = 0; n < 4; ++n)
            #pragma unroll
            for (int k = 0; k < 2; ++k){
                int d = d0 + n*16 + fr;
                ht[n][k] = *(const short8v*)((const char*)regA + (size_t)d*128 + (((k*32+fk)*2) ^ ((d&7)<<4)));
            }
        #pragma unroll
        for (int k = 0; k < 2; ++k)
            #pragma unroll
            for (int m = 0; m < 4; ++m)
                #pragma unroll
                for (int n = 0; n < 4; ++n)
                    acc[m][n] = __builtin_amdgcn_mfma_f32_16x16x32_bf16(aw[m][k], ht[n][k], acc[m][n], 0, 0, 0);
    }

    // ---- epilogue: + D*x, * silu(z) ----
    float Dh = Dp[h];
    #pragma unroll
    for (int m = 0; m < 4; ++m)
        #pragma unroll
        for (int n = 0; n < 4; ++n)
            #pragma unroll
            for (int i = 0; i < 4; ++i){
                int t = m*16 + rr + i;
                int d = d0 + n*16 + rc;
                size_t off = (size_t)(b*SEQ + t0 + t)*D_INNER + h*D_HEAD + d;
                float val = acc[m][n][i] + Dh * bf2f(xs[off]);
                y[off] = f2bf_bits(val * silu_f(bf2f(z[off])));
            }
}

// ---------------- launch ----------------
extern "C" void kernel_launch(void* const* d_in, const int* in_sizes, int n_in,
                              void* d_out, int out_size, void* d_ws, size_t ws_size,
                              hipStream_t stream){
    const float* x      = (const float*)d_in[0];
    const float* norm_w = (const float*)d_in[1];
    const float* in_w   = (const float*)d_in[2];
    const float* conv_w = (const float*)d_in[3];
    const float* conv_b = (const float*)d_in[4];
    const float* A_log  = (const float*)d_in[5];
    const float* B_w    = (const float*)d_in[6];
    const float* C_w    = (const float*)d_in[7];
    const float* dt_w   = (const float*)d_in[8];
    const float* dt_b   = (const float*)d_in[9];
    const float* Dp     = (const float*)d_in[10];
    const float* out_w  = (const float*)d_in[11];
    float* out = (float*)d_out;

    char* ws = (char*)d_ws;
    const size_t MB = 1048576ull;
    unsigned short* xpre_bf = (unsigned short*)(ws);             // [0,16) ; reused as y
    unsigned short* y_bf    = xpre_bf;
    unsigned short* z_bf    = (unsigned short*)(ws + 16*MB);     // [16,32)
    unsigned short* xs_bf   = (unsigned short*)(ws + 32*MB);     // [32,48)
    unsigned short* inw_bf  = (unsigned short*)(ws + 48*MB);     // [48,56) dead before xdT written
    unsigned short* xdT     = (unsigned short*)(ws + 48*MB);     // [48,64)
    float*          HS      = (float*)(ws + 64*MB);              // [64,96)
    unsigned short* Bm      = (unsigned short*)(ws + 96*MB);     // [96,100)
    unsigned short* Cm      = (unsigned short*)(ws + 100*MB);    // [100,104)
    unsigned short* outw_bf = (unsigned short*)(ws + 104*MB);    // [104,108)
    unsigned short* Bw_bf   = (unsigned short*)(ws + 108*MB);    // [108,110)
    unsigned short* Cw_bf   = (unsigned short*)(ws + 110*MB);    // [110,112)
    unsigned short* xn_bf   = (unsigned short*)(ws + 112*MB);    // [112,120)
    float*          dtb     = (float*)(ws + 120*MB);             // 128 KB
    float*          cums    = (float*)(ws + 120*MB + 131072);    // 128 KB

    f2bf_kernel<<<4096, 256, 0, stream>>>(in_w,  inw_bf,  D_INNER*2*D_MODEL/4);
    f2bf_kernel<<<2048, 256, 0, stream>>>(out_w, outw_bf, D_MODEL*D_INNER/4);
    f2bf_kernel<<<1024, 256, 0, stream>>>(B_w, Bw_bf, 512*D_INNER/4);
    f2bf_kernel<<<1024, 256, 0, stream>>>(C_w, Cw_bf, 512*D_INNER/4);

    rmsnorm_kernel<<<ROWS, 256, 0, stream>>>(x, norm_w, xn_bf);

    gemm_mfma<0><<<dim3(16,32), 256, 0, stream>>>(xn_bf, inw_bf, xpre_bf, nullptr,
        ROWS, D_INNER, D_MODEL);
    gemm_mfma<0><<<dim3(16,32), 256, 0, stream>>>(xn_bf, inw_bf + (size_t)D_INNER*D_MODEL, z_bf, nullptr,
        ROWS, D_INNER, D_MODEL);

    conv_silu_kernel<<<(ROWS*D_INNER)/256, 256, 0, stream>>>(xpre_bf, conv_w, conv_b, xs_bf);

    dt_kernel<<<ROWS, 256, 0, stream>>>(xs_bf, dt_w, dt_b, dtb);

    gemm_mfma<0><<<dim3(4,32), 256, 0, stream>>>(xs_bf, Bw_bf, Bm, nullptr, ROWS, 512, D_INNER);
    gemm_mfma<0><<<dim3(4,32), 256, 0, stream>>>(xs_bf, Cw_bf, Cm, nullptr, ROWS, 512, D_INNER);

    cums_kernel<<<dim3(NCHUNK, N_HEADS, BATCH), 64, 0, stream>>>(dtb, A_log, cums);

    xdT_kernel<<<dim3(SEQ/64, D_HEAD/64, BATCH*N_HEADS), 256, 0, stream>>>(xs_bf, dtb, xdT);

    chunk_state_mfma<<<dim3(NCHUNK, N_HEADS, BATCH), 256, 0, stream>>>(xdT, Bm, cums, HS);

    state_pass_kernel<<<dim3(64, BATCH*N_HEADS), 256, 0, stream>>>(cums, HS);

    chunk_out_mfma<<<dim3(NCHUNK, N_HEADS, BATCH), 256, 0, stream>>>(xs_bf, z_bf, Bm, Cm, xdT, cums, HS, Dp, y_bf);

    gemm_mfma<2><<<dim3(8,32), 256, 0, stream>>>(y_bf, outw_bf, out, x,
        ROWS, D_MODEL, D_INNER);
}

// Round 5
// 269.138 us; speedup vs baseline: 9.7751x; 1.2746x over previous
//
#include <hip/hip_runtime.h>
#include <hip/hip_bf16.h>
#include <math.h>

#define D_MODEL 1024
#define D_STATE 64
#define D_CONV  4
#define D_INNER 2048
#define N_HEADS 8
#define D_HEAD  256
#define BATCH   2
#define SEQ     2048
#define ROWS    (BATCH*SEQ)   /* 4096 */
#define NCHUNK  32            /* SEQ/64 */
#define EPS     1e-6f

typedef __attribute__((ext_vector_type(4))) unsigned short ushort4v;
typedef __attribute__((ext_vector_type(8))) unsigned short ushort8v;
typedef __attribute__((ext_vector_type(8))) short short8v;
typedef __attribute__((ext_vector_type(4))) float f32x4;

__device__ __forceinline__ float silu_f(float x){ return x / (1.0f + __expf(-x)); }
__device__ __forceinline__ float softplus_f(float x){ return (x > 20.0f) ? x : log1pf(__expf(x)); }
__device__ __forceinline__ float bf2f(unsigned short u){
    union { unsigned int i; float f; } v; v.i = ((unsigned int)u) << 16; return v.f;
}
__device__ __forceinline__ unsigned short f2bf_bits(float f){
    __hip_bfloat16 h = __float2bfloat16(f);
    return *(unsigned short*)&h;
}
__device__ __forceinline__ void gload_lds16(const void* g, void* l){
    __builtin_amdgcn_global_load_lds((const __attribute__((address_space(1))) void*)g,
                                     (__attribute__((address_space(3))) void*)l, 16, 0, 0);
}

// ---------------- fp32 -> bf16 convert (weights) ----------------
__global__ __launch_bounds__(256) void f2bf_kernel(const float* __restrict__ src,
                                                   unsigned short* __restrict__ dst, int n4){
    int i = blockIdx.x * 256 + threadIdx.x;
    if (i < n4){
        float4 v = ((const float4*)src)[i];
        ushort4v o;
        o[0] = f2bf_bits(v.x); o[1] = f2bf_bits(v.y);
        o[2] = f2bf_bits(v.z); o[3] = f2bf_bits(v.w);
        ((ushort4v*)dst)[i] = o;
    }
}

// ---------------- RMSNorm -> bf16 ----------------
__global__ __launch_bounds__(256) void rmsnorm_kernel(const float* __restrict__ x,
                                                      const float* __restrict__ w,
                                                      unsigned short* __restrict__ xn){
    int row = blockIdx.x;
    int tid = threadIdx.x;
    const float4* xr = (const float4*)(x + (size_t)row * D_MODEL);
    float4 a = xr[tid];
    float ss = a.x*a.x + a.y*a.y + a.z*a.z + a.w*a.w;
    #pragma unroll
    for (int i = 1; i < 64; i <<= 1) ss += __shfl_xor(ss, i);
    __shared__ float red[4];
    int lane = tid & 63, wid = tid >> 6;
    if (lane == 0) red[wid] = ss;
    __syncthreads();
    float tot = red[0] + red[1] + red[2] + red[3];
    float scale = rsqrtf(tot * (1.0f / D_MODEL) + EPS);
    float4 wv = ((const float4*)w)[tid];
    ushort4v o;
    o[0] = f2bf_bits(a.x * scale * wv.x);
    o[1] = f2bf_bits(a.y * scale * wv.y);
    o[2] = f2bf_bits(a.z * scale * wv.z);
    o[3] = f2bf_bits(a.w * scale * wv.w);
    ((ushort4v*)(xn + (size_t)row * D_MODEL))[tid] = o;
}

// ---------------- bf16 MFMA NT GEMM, BK=64, swizzled LDS, XCD-swizzled grid ----------------
// MODE 0: bf16 out (Cout0, ldc=N). MODE 1: split bf16 out at col 2048 (xpre/z, ldc=2048).
// MODE 2: f32 out + f32 residual (ldc=N).
template<int MODE>
__global__ __launch_bounds__(256) void gemm_mfma(const unsigned short* __restrict__ A,
                                                 const unsigned short* __restrict__ W,
                                                 void* __restrict__ Cout0,
                                                 void* __restrict__ Cout1,
                                                 const float* __restrict__ resid,
                                                 int M, int N, int K, int NX){
    __shared__ unsigned short As[128*64];
    __shared__ unsigned short Bs[128*64];
    int tid = threadIdx.x;
    // bijective XCD swizzle (gridDim.x % 8 == 0)
    int bid = blockIdx.x;
    int cpx = gridDim.x >> 3;
    int sw = (bid & 7)*cpx + (bid >> 3);
    int m0 = (sw / NX) * 128, n0 = (sw % NX) * 128;

    int lane = tid & 63;
    int wave = tid >> 6;
    int wr = wave >> 1, wc = wave & 1;
    f32x4 acc[4][4];
    #pragma unroll
    for (int i = 0; i < 4; ++i)
        #pragma unroll
        for (int j = 0; j < 4; ++j) acc[i][j] = (f32x4){0.f,0.f,0.f,0.f};

    // staging: 8 chunks of 16B per 128B row; source pre-swizzled by ((row&7)<<4)
    int srow = tid >> 3;          // 0..31
    int sseg = tid & 7;
    int soff = ((sseg*16) ^ ((srow&7)<<4)) >> 1;    // elements
    const unsigned short* aS = A + (size_t)(m0 + srow)*K + soff;
    const unsigned short* bS = W + (size_t)(n0 + srow)*K + soff;
    char* aD = (char*)As + (size_t)tid*16;
    char* bD = (char*)Bs + (size_t)tid*16;

    int frow = lane & 15;
    int fkb  = (lane >> 4) * 16;    // byte offset of lane's 8 elems within 32-elem slice

    for (int k0 = 0; k0 < K; k0 += 64){
        #pragma unroll
        for (int it = 0; it < 4; ++it){
            gload_lds16(aS + (size_t)(it*32)*K + k0, aD + it*4096);
            gload_lds16(bS + (size_t)(it*32)*K + k0, bD + it*4096);
        }
        __syncthreads();
        short8v af[2][4], bf[2][4];
        #pragma unroll
        for (int m = 0; m < 4; ++m){
            int r = wr*64 + m*16 + frow;
            #pragma unroll
            for (int k = 0; k < 2; ++k)
                af[k][m] = *(const short8v*)((const char*)As + (size_t)r*128 + ((k*64 + fkb) ^ ((r&7)<<4)));
        }
        #pragma unroll
        for (int n = 0; n < 4; ++n){
            int r = wc*64 + n*16 + frow;
            #pragma unroll
            for (int k = 0; k < 2; ++k)
                bf[k][n] = *(const short8v*)((const char*)Bs + (size_t)r*128 + ((k*64 + fkb) ^ ((r&7)<<4)));
        }
        #pragma unroll
        for (int k = 0; k < 2; ++k)
            #pragma unroll
            for (int m = 0; m < 4; ++m)
                #pragma unroll
                for (int n = 0; n < 4; ++n)
                    acc[m][n] = __builtin_amdgcn_mfma_f32_16x16x32_bf16(af[k][m], bf[k][n], acc[m][n], 0, 0, 0);
        __syncthreads();
    }

    int rrow = (lane >> 4) * 4;
    int rcol = lane & 15;
    if (MODE == 2){
        float* Co = (float*)Cout0;
        #pragma unroll
        for (int m = 0; m < 4; ++m)
            #pragma unroll
            for (int n = 0; n < 4; ++n){
                int cc = n0 + wc*64 + n*16 + rcol;
                #pragma unroll
                for (int i = 0; i < 4; ++i){
                    int rr = m0 + wr*64 + m*16 + rrow + i;
                    Co[(size_t)rr*N + cc] = acc[m][n][i] + resid[(size_t)rr*N + cc];
                }
            }
    } else {
        unsigned short* outp;
        int colbase, ldc;
        if (MODE == 1){
            if (n0 < 2048){ outp = (unsigned short*)Cout0; colbase = n0; }
            else          { outp = (unsigned short*)Cout1; colbase = n0 - 2048; }
            ldc = 2048;
        } else {
            outp = (unsigned short*)Cout0; colbase = n0; ldc = N;
        }
        #pragma unroll
        for (int m = 0; m < 4; ++m)
            #pragma unroll
            for (int n = 0; n < 4; ++n){
                int cc = colbase + wc*64 + n*16 + rcol;
                #pragma unroll
                for (int i = 0; i < 4; ++i){
                    int rr = m0 + wr*64 + m*16 + rrow + i;
                    outp[(size_t)rr*ldc + cc] = f2bf_bits(acc[m][n][i]);
                }
            }
    }
}

// ---------------- depthwise causal conv (K=4) + SiLU, bf16 in/out ----------------
__global__ __launch_bounds__(256) void conv_silu_kernel(const unsigned short* __restrict__ xp,
                                                        const float* __restrict__ cw,
                                                        const float* __restrict__ cb,
                                                        unsigned short* __restrict__ xs){
    int idx = blockIdx.x * 256 + threadIdx.x;
    int c = idx & (D_INNER - 1);
    int r = idx >> 11;
    int t = r & (SEQ - 1);
    float acc = cb[c];
    #pragma unroll
    for (int j = 0; j < 4; ++j){
        int tt = t - 3 + j;
        if (tt >= 0) acc += bf2f(xp[(size_t)(r - 3 + j)*D_INNER + c]) * cw[c*4 + j];
    }
    xs[idx] = f2bf_bits(silu_f(acc));
}

// ---------------- dt = softplus(xs @ dt_w^T + dt_b) ----------------
__global__ __launch_bounds__(256) void dt_kernel(const unsigned short* __restrict__ xs,
                                                 const float* __restrict__ dt_w,
                                                 const float* __restrict__ dt_b,
                                                 float* __restrict__ dt){
    __shared__ float sx[D_INNER];
    __shared__ float red[4];
    int row = blockIdx.x, tid = threadIdx.x;
    ushort8v v = ((const ushort8v*)(xs + (size_t)row * D_INNER))[tid];
    #pragma unroll
    for (int j = 0; j < 8; ++j) sx[tid*8 + j] = bf2f(v[j]);
    __syncthreads();
    int lane = tid & 63, wid = tid >> 6;
    for (int h = 0; h < N_HEADS; ++h){
        float p = 0.f;
        for (int k = tid; k < D_INNER; k += 256) p += sx[k] * dt_w[h*D_INNER + k];
        #pragma unroll
        for (int i = 1; i < 64; i <<= 1) p += __shfl_xor(p, i);
        if (lane == 0) red[wid] = p;
        __syncthreads();
        if (tid == 0){
            float s = red[0]+red[1]+red[2]+red[3] + dt_b[h];
            dt[(size_t)row*N_HEADS + h] = softplus_f(s);
        }
        __syncthreads();
    }
}

// ---------------- per-chunk inclusive prefix of a_t = dt_t * A_h ----------------
__global__ __launch_bounds__(64) void cums_kernel(const float* __restrict__ dtb,
                                                  const float* __restrict__ A_log,
                                                  float* __restrict__ cums){
    int c = blockIdx.x, h = blockIdx.y, b = blockIdx.z;
    int lane = threadIdx.x;
    int t = c*64 + lane;
    float Ah = -__expf(A_log[h]);
    float a = dtb[(size_t)(b*SEQ + t)*N_HEADS + h] * Ah;
    #pragma unroll
    for (int i = 1; i < 64; i <<= 1){
        float v = __shfl_up(a, i);
        if (lane >= i) a += v;
    }
    cums[((size_t)(b*N_HEADS + h))*SEQ + t] = a;
}

// ---------------- xdT: [bh][d][t] bf16 = xs * dt, transposed ----------------
__global__ __launch_bounds__(256) void xdT_kernel(const unsigned short* __restrict__ xs,
                                                  const float* __restrict__ dtb,
                                                  unsigned short* __restrict__ xdT){
    int ct = blockIdx.x, cd = blockIdx.y, bh = blockIdx.z;
    int b = bh >> 3, h = bh & 7;
    __shared__ unsigned short sT[64*68];
    int tid = threadIdx.x;
    #pragma unroll
    for (int it = 0; it < 2; ++it){
        int l = tid + it*256;
        int tl = l >> 3, seg = l & 7;
        int row = b*SEQ + ct*64 + tl;
        ushort8v v = *(const ushort8v*)(xs + (size_t)row*D_INNER + h*D_HEAD + cd*64 + seg*8);
        float dtv = dtb[(size_t)row*N_HEADS + h];
        ushort4v lo, hi;
        #pragma unroll
        for (int j = 0; j < 4; ++j){
            lo[j] = f2bf_bits(bf2f(v[j]) * dtv);
            hi[j] = f2bf_bits(bf2f(v[j+4]) * dtv);
        }
        *(ushort4v*)((char*)sT + tl*136 + seg*16)     = lo;
        *(ushort4v*)((char*)sT + tl*136 + seg*16 + 8) = hi;
    }
    __syncthreads();
    #pragma unroll
    for (int it = 0; it < 2; ++it){
        int l = tid + it*256;
        int dl = l >> 3, tseg = l & 7;
        ushort8v o;
        #pragma unroll
        for (int j = 0; j < 8; ++j) o[j] = sT[(tseg*8 + j)*68 + dl];
        *(ushort8v*)(xdT + ((size_t)bh*D_HEAD + cd*64 + dl)*SEQ + ct*64 + tseg*8) = o;
    }
}

// ---------------- chunk_state (MFMA): HS[bh][c][d][n] = sum_t XdT[d][t]*Bdecay[t][n] ----------------
__global__ __launch_bounds__(256) void chunk_state_mfma(const unsigned short* __restrict__ xdT,
                                                        const unsigned short* __restrict__ BCm,
                                                        const float* __restrict__ cums,
                                                        float* __restrict__ HS){
    int c = blockIdx.x, h = blockIdx.y, b = blockIdx.z;
    int tid = threadIdx.x;
    int bh = b*N_HEADS + h;
    int t0 = c*64;
    __shared__ unsigned short sX[256*64];
    __shared__ unsigned short sBdT[64*72];
    __shared__ float sdec[64];
    if (tid < 64)
        sdec[tid] = __expf(cums[(size_t)bh*SEQ + t0 + 63] - cums[(size_t)bh*SEQ + t0 + tid]);
    const unsigned short* xb = xdT + (size_t)bh*D_HEAD*SEQ + t0;
    #pragma unroll
    for (int it = 0; it < 8; ++it){
        int l = tid + it*256;
        int d = l >> 3, seg = l & 7;
        gload_lds16(xb + (size_t)d*SEQ + (((seg*16) ^ ((d&7)<<4)) >> 1),
                    (char*)sX + (size_t)l*16);
    }
    __syncthreads();
    #pragma unroll
    for (int it = 0; it < 2; ++it){
        int l = tid + it*256;
        int tl = l >> 3, seg = l & 7;
        ushort8v bv = *(const ushort8v*)(BCm + (size_t)(b*SEQ + t0 + tl)*1024 + h*64 + seg*8);
        float dec = sdec[tl];
        #pragma unroll
        for (int j = 0; j < 8; ++j)
            sBdT[(seg*8 + j)*72 + tl] = f2bf_bits(bf2f(bv[j]) * dec);
    }
    __syncthreads();

    int lane = tid & 63, w = tid >> 6;
    int d0 = w*64;
    int fr = lane & 15, fk = (lane >> 4)*8;
    f32x4 acc[4][4];
    #pragma unroll
    for (int i = 0; i < 4; ++i)
        #pragma unroll
        for (int j = 0; j < 4; ++j) acc[i][j] = (f32x4){0.f,0.f,0.f,0.f};
    short8v af[4][2], bg[4][2];
    #pragma unroll
    for (int m = 0; m < 4; ++m)
        #pragma unroll
        for (int k = 0; k < 2; ++k){
            int d = d0 + m*16 + fr;
            af[m][k] = *(const short8v*)((const char*)sX + (size_t)d*128 + (((k*32+fk)*2) ^ ((d&7)<<4)));
        }
    #pragma unroll
    for (int n = 0; n < 4; ++n)
        #pragma unroll
        for (int k = 0; k < 2; ++k)
            bg[n][k] = *(const short8v*)(sBdT + (size_t)(n*16 + fr)*72 + k*32 + fk);
    #pragma unroll
    for (int k = 0; k < 2; ++k)
        #pragma unroll
        for (int m = 0; m < 4; ++m)
            #pragma unroll
            for (int n = 0; n < 4; ++n)
                acc[m][n] = __builtin_amdgcn_mfma_f32_16x16x32_bf16(af[m][k], bg[n][k], acc[m][n], 0, 0, 0);

    float* out = HS + ((size_t)bh*NCHUNK + c)*16384;
    int rr = (lane >> 4)*4, rc = lane & 15;
    #pragma unroll
    for (int m = 0; m < 4; ++m)
        #pragma unroll
        for (int n = 0; n < 4; ++n)
            #pragma unroll
            for (int i = 0; i < 4; ++i)
                out[(size_t)(d0 + m*16 + rr + i)*64 + n*16 + rc] = acc[m][n][i];
}

// ---------------- chunk recurrence: HS[c] := H_start(c) ----------------
__global__ __launch_bounds__(256) void state_pass_kernel(const float* __restrict__ cums,
                                                         float* __restrict__ HS){
    int e  = blockIdx.x*256 + threadIdx.x;
    int bh = blockIdx.y;
    float H = 0.f;
    float* p = HS + (size_t)bh*NCHUNK*16384 + e;
    const float* cp = cums + (size_t)bh*SEQ + 63;
    for (int c = 0; c < NCHUNK; ++c){
        float Pc = __expf(cp[(size_t)c*64]);
        float s = *p;
        *p = H;
        H = fmaf(Pc, H, s);
        p += 16384;
    }
}

// ---------------- chunk_out (MFMA) ----------------
__global__ __launch_bounds__(256) void chunk_out_mfma(const unsigned short* __restrict__ xs,
                                                      const unsigned short* __restrict__ z,
                                                      const unsigned short* __restrict__ BCm,
                                                      const unsigned short* __restrict__ xdT,
                                                      const float* __restrict__ cums,
                                                      const float* __restrict__ HS,
                                                      const float* __restrict__ Dp,
                                                      unsigned short* __restrict__ y){
    int c = blockIdx.x, h = blockIdx.y, b = blockIdx.z;
    int tid = threadIdx.x;
    int bh = b*N_HEADS + h;
    int t0 = c*64;
    __shared__ unsigned short regA[256*64];
    __shared__ unsigned short sW[64*64];
    __shared__ unsigned short sCd[64*64];
    __shared__ float scum[64];
    unsigned short* Craw = regA;
    unsigned short* Braw = regA + 64*64;

    if (tid < 64) scum[tid] = cums[(size_t)bh*SEQ + t0 + tid];
    #pragma unroll
    for (int it = 0; it < 2; ++it){
        int l = tid + it*256;
        int tl = l >> 3, seg = l & 7;
        size_t rowoff = (size_t)(b*SEQ + t0 + tl)*1024 + h*64;
        int soff = ((seg*16) ^ ((tl&7)<<4)) >> 1;
        gload_lds16(BCm + rowoff + 512 + soff, (char*)Craw + (size_t)l*16);
        gload_lds16(BCm + rowoff + soff,       (char*)Braw + (size_t)l*16);
    }
    __syncthreads();

    int lane = tid & 63, w = tid >> 6;
    int fr = lane & 15, fk = (lane >> 4)*8;
    int rr = (lane >> 4)*4, rc = lane & 15;

    int wr = w >> 1, wc = w & 1;
    f32x4 g[2][2];
    #pragma unroll
    for (int i = 0; i < 2; ++i)
        #pragma unroll
        for (int j = 0; j < 2; ++j) g[i][j] = (f32x4){0.f,0.f,0.f,0.f};
    {
        short8v ca[2][2], bb[2][2];
        #pragma unroll
        for (int m = 0; m < 2; ++m)
            #pragma unroll
            for (int k = 0; k < 2; ++k){
                int t = wr*32 + m*16 + fr;
                ca[m][k] = *(const short8v*)((const char*)Craw + (size_t)t*128 + (((k*32+fk)*2) ^ ((t&7)<<4)));
            }
        #pragma unroll
        for (int n = 0; n < 2; ++n)
            #pragma unroll
            for (int k = 0; k < 2; ++k){
                int s = wc*32 + n*16 + fr;
                bb[n][k] = *(const short8v*)((const char*)Braw + (size_t)s*128 + (((k*32+fk)*2) ^ ((s&7)<<4)));
            }
        #pragma unroll
        for (int k = 0; k < 2; ++k)
            #pragma unroll
            for (int m = 0; m < 2; ++m)
                #pragma unroll
                for (int n = 0; n < 2; ++n)
                    g[m][n] = __builtin_amdgcn_mfma_f32_16x16x32_bf16(ca[m][k], bb[n][k], g[m][n], 0, 0, 0);
    }
    #pragma unroll
    for (int m = 0; m < 2; ++m)
        #pragma unroll
        for (int n = 0; n < 2; ++n)
            #pragma unroll
            for (int i = 0; i < 4; ++i){
                int t = wr*32 + m*16 + rr + i;
                int s = wc*32 + n*16 + rc;
                float wv = (s <= t) ? __expf(scum[t] - scum[s]) * g[m][n][i] : 0.f;
                *(unsigned short*)((char*)sW + (size_t)t*128 + ((s*2) ^ ((t&7)<<4))) = f2bf_bits(wv);
            }
    {
        int tl = tid >> 2, sg = tid & 3;
        float ef = __expf(scum[tl]);
        #pragma unroll
        for (int q = 0; q < 2; ++q){
            int off = ((sg*32 + q*16)) ^ ((tl&7)<<4);
            ushort8v cv = *(const ushort8v*)((const char*)Craw + (size_t)tl*128 + off);
            ushort8v ov;
            #pragma unroll
            for (int j = 0; j < 8; ++j) ov[j] = f2bf_bits(bf2f(cv[j]) * ef);
            *(ushort8v*)((char*)sCd + (size_t)tl*128 + off) = ov;
        }
    }
    __syncthreads();

    const unsigned short* xb = xdT + (size_t)bh*D_HEAD*SEQ + t0;
    #pragma unroll
    for (int it = 0; it < 8; ++it){
        int l = tid + it*256;
        int d = l >> 3, seg = l & 7;
        gload_lds16(xb + (size_t)d*SEQ + (((seg*16) ^ ((d&7)<<4)) >> 1),
                    (char*)regA + (size_t)l*16);
    }
    __syncthreads();

    int d0 = w*64;
    f32x4 acc[4][4];
    #pragma unroll
    for (int i = 0; i < 4; ++i)
        #pragma unroll
        for (int j = 0; j < 4; ++j) acc[i][j] = (f32x4){0.f,0.f,0.f,0.f};
    {
        short8v aw[4][2], xd[4][2];
        #pragma unroll
        for (int m = 0; m < 4; ++m)
            #pragma unroll
            for (int k = 0; k < 2; ++k){
                int t = m*16 + fr;
                aw[m][k] = *(const short8v*)((const char*)sW + (size_t)t*128 + (((k*32+fk)*2) ^ ((t&7)<<4)));
            }
        #pragma unroll
        for (int n = 0; n < 4; ++n)
            #pragma unroll
            for (int k = 0; k < 2; ++k){
                int d = d0 + n*16 + fr;
                xd[n][k] = *(const short8v*)((const char*)regA + (size_t)d*128 + (((k*32+fk)*2) ^ ((d&7)<<4)));
            }
        #pragma unroll
        for (int k = 0; k < 2; ++k)
            #pragma unroll
            for (int m = 0; m < 4; ++m)
                #pragma unroll
                for (int n = 0; n < 4; ++n)
                    acc[m][n] = __builtin_amdgcn_mfma_f32_16x16x32_bf16(aw[m][k], xd[n][k], acc[m][n], 0, 0, 0);
    }
    __syncthreads();

    size_t hsbase = ((size_t)bh*NCHUNK + c)*16384;
    {
        int q = tid >> 4, s16 = tid & 15;
        const float* hp = HS + hsbase;
        #pragma unroll
        for (int db = 0; db < 16; ++db){
            int d = db*16 + q;
            float4 hv = *(const float4*)(hp + (size_t)d*64 + s16*4);
            ushort4v ov;
            ov[0] = f2bf_bits(hv.x); ov[1] = f2bf_bits(hv.y);
            ov[2] = f2bf_bits(hv.z); ov[3] = f2bf_bits(hv.w);
            *(ushort4v*)((char*)regA + (size_t)d*128 + ((s16*8) ^ ((d&7)<<4))) = ov;
        }
    }
    __syncthreads();

    {
        short8v aw[4][2], ht[4][2];
        #pragma unroll
        for (int m = 0; m < 4; ++m)
            #pragma unroll
            for (int k = 0; k < 2; ++k){
                int t = m*16 + fr;
                aw[m][k] = *(const short8v*)((const char*)sCd + (size_t)t*128 + (((k*32+fk)*2) ^ ((t&7)<<4)));
            }
        #pragma unroll
        for (int n = 0; n < 4; ++n)
            #pragma unroll
            for (int k = 0; k < 2; ++k){
                int d = d0 + n*16 + fr;
                ht[n][k] = *(const short8v*)((const char*)regA + (size_t)d*128 + (((k*32+fk)*2) ^ ((d&7)<<4)));
            }
        #pragma unroll
        for (int k = 0; k < 2; ++k)
            #pragma unroll
            for (int m = 0; m < 4; ++m)
                #pragma unroll
                for (int n = 0; n < 4; ++n)
                    acc[m][n] = __builtin_amdgcn_mfma_f32_16x16x32_bf16(aw[m][k], ht[n][k], acc[m][n], 0, 0, 0);
    }

    float Dh = Dp[h];
    #pragma unroll
    for (int m = 0; m < 4; ++m)
        #pragma unroll
        for (int n = 0; n < 4; ++n)
            #pragma unroll
            for (int i = 0; i < 4; ++i){
                int t = m*16 + rr + i;
                int d = d0 + n*16 + rc;
                size_t off = (size_t)(b*SEQ + t0 + t)*D_INNER + h*D_HEAD + d;
                float val = acc[m][n][i] + Dh * bf2f(xs[off]);
                y[off] = f2bf_bits(val * silu_f(bf2f(z[off])));
            }
}

// ---------------- launch ----------------
extern "C" void kernel_launch(void* const* d_in, const int* in_sizes, int n_in,
                              void* d_out, int out_size, void* d_ws, size_t ws_size,
                              hipStream_t stream){
    const float* x      = (const float*)d_in[0];
    const float* norm_w = (const float*)d_in[1];
    const float* in_w   = (const float*)d_in[2];
    const float* conv_w = (const float*)d_in[3];
    const float* conv_b = (const float*)d_in[4];
    const float* A_log  = (const float*)d_in[5];
    const float* B_w    = (const float*)d_in[6];
    const float* C_w    = (const float*)d_in[7];
    const float* dt_w   = (const float*)d_in[8];
    const float* dt_b   = (const float*)d_in[9];
    const float* Dp     = (const float*)d_in[10];
    const float* out_w  = (const float*)d_in[11];
    float* out = (float*)d_out;

    char* ws = (char*)d_ws;
    const size_t MB = 1048576ull;
    unsigned short* xpre_bf = (unsigned short*)(ws);             // [0,16) ; reused as y
    unsigned short* y_bf    = xpre_bf;
    unsigned short* z_bf    = (unsigned short*)(ws + 16*MB);     // [16,32)
    unsigned short* xs_bf   = (unsigned short*)(ws + 32*MB);     // [32,48)
    unsigned short* inw_bf  = (unsigned short*)(ws + 48*MB);     // [48,56) dead before xdT written
    unsigned short* xdT     = (unsigned short*)(ws + 48*MB);     // [48,64)
    float*          HS      = (float*)(ws + 64*MB);              // [64,96)
    unsigned short* BCm     = (unsigned short*)(ws + 96*MB);     // [96,104)
    unsigned short* outw_bf = (unsigned short*)(ws + 104*MB);    // [104,108)
    unsigned short* BCw_bf  = (unsigned short*)(ws + 108*MB);    // [108,112)
    unsigned short* xn_bf   = (unsigned short*)(ws + 112*MB);    // [112,120)
    float*          dtb     = (float*)(ws + 120*MB);             // 128 KB
    float*          cums    = (float*)(ws + 120*MB + 131072);    // 128 KB

    f2bf_kernel<<<4096, 256, 0, stream>>>(in_w,  inw_bf,  D_INNER*2*D_MODEL/4);
    f2bf_kernel<<<2048, 256, 0, stream>>>(out_w, outw_bf, D_MODEL*D_INNER/4);
    f2bf_kernel<<<1024, 256, 0, stream>>>(B_w, BCw_bf, 512*D_INNER/4);
    f2bf_kernel<<<1024, 256, 0, stream>>>(C_w, BCw_bf + (size_t)512*D_INNER, 512*D_INNER/4);

    rmsnorm_kernel<<<ROWS, 256, 0, stream>>>(x, norm_w, xn_bf);

    // fused in_proj: N = 4096, split outputs
    gemm_mfma<1><<<1024, 256, 0, stream>>>(xn_bf, inw_bf, xpre_bf, z_bf, nullptr,
        ROWS, 2*D_INNER, D_MODEL, 32);

    conv_silu_kernel<<<(ROWS*D_INNER)/256, 256, 0, stream>>>(xpre_bf, conv_w, conv_b, xs_bf);

    dt_kernel<<<ROWS, 256, 0, stream>>>(xs_bf, dt_w, dt_b, dtb);

    // fused B/C projection: N = 1024
    gemm_mfma<0><<<256, 256, 0, stream>>>(xs_bf, BCw_bf, BCm, nullptr, nullptr,
        ROWS, 1024, D_INNER, 8);

    cums_kernel<<<dim3(NCHUNK, N_HEADS, BATCH), 64, 0, stream>>>(dtb, A_log, cums);

    xdT_kernel<<<dim3(SEQ/64, D_HEAD/64, BATCH*N_HEADS), 256, 0, stream>>>(xs_bf, dtb, xdT);

    chunk_state_mfma<<<dim3(NCHUNK, N_HEADS, BATCH), 256, 0, stream>>>(xdT, BCm, cums, HS);

    state_pass_kernel<<<dim3(64, BATCH*N_HEADS), 256, 0, stream>>>(cums, HS);

    chunk_out_mfma<<<dim3(NCHUNK, N_HEADS, BATCH), 256, 0, stream>>>(xs_bf, z_bf, BCm, xdT, cums, HS, Dp, y_bf);

    gemm_mfma<2><<<256, 256, 0, stream>>>(y_bf, outw_bf, out, nullptr, x,
        ROWS, D_MODEL, D_INNER, 8);
}